// Round 2
// 158.092 us; speedup vs baseline: 1.0686x; 1.0686x over previous
//
#include <hip/hip_runtime.h>

// Problem constants
#define BATCH 8
#define CCH   384      // channels C == INNER
#define NTOK  1024     // H*W
#define HEADS 6
#define DHEAD 64
// softmax scale 1/8 and log2(e) folded into Q at projection time:
// qout = Q * 0.125 * 1.4426950408889634, attn uses exp2(s) = bare v_exp.
#define QSCALE 0.18033688011112042f

typedef __bf16 bf16x8 __attribute__((ext_vector_type(8)));
typedef float  f32x4  __attribute__((ext_vector_type(4)));
typedef float  f32x16 __attribute__((ext_vector_type(16)));

#define MFMA16(a, b, c) __builtin_amdgcn_mfma_f32_16x16x32_bf16((a), (b), (c), 0, 0, 0)
#define MFMA32(a, b, c) __builtin_amdgcn_mfma_f32_32x32x16_bf16((a), (b), (c), 0, 0, 0)
#define EXP2(x) __builtin_amdgcn_exp2f(x)

// fp32 -> bf16 RNE, raw bits
__device__ __forceinline__ short f2b(float x) {
    unsigned u = __float_as_uint(x);
    u += 0x7fffu + ((u >> 16) & 1u);
    return (short)(u >> 16);
}

// async global->LDS, 16B/lane. LDS dst = wave-uniform base + lane*16.
__device__ __forceinline__ void gld_lds16(const short* gp, short* lp) {
    __builtin_amdgcn_global_load_lds(
        (const __attribute__((address_space(1))) void*)gp,
        (__attribute__((address_space(3))) void*)lp, 16, 0, 0);
}

// ---- 64x64 xor-swizzled tile staging (4 waves) — verified r3/r4 ----
__device__ __forceinline__ void stage_tile(const short* gbase, size_t gstride,
                                           short* lbase, int wv, int lane) {
#pragma unroll
    for (int t = 0; t < 2; ++t) {
        const int row = t * 8 + (lane >> 3);
        const int c   = (lane & 7) ^ (row & 7);
        gld_lds16(gbase + (size_t)(wv * 16 + row) * gstride + c * 8,
                  lbase + (wv * 16 + t * 8) * 64);
    }
}
// same tile, staged by 2 waves (sw = 0/1), 4 gld per thread
__device__ __forceinline__ void stage_tile_2w(const short* gbase, size_t gstride,
                                              short* lbase, int sw, int lane) {
#pragma unroll
    for (int t = 0; t < 4; ++t) {
        const int row = sw * 32 + t * 8 + (lane >> 3);
        const int c   = (lane & 7) ^ (row & 7);
        gld_lds16(gbase + (size_t)row * gstride + c * 8,
                  lbase + (sw * 32 + t * 8) * 64);
    }
}
__device__ __forceinline__ bf16x8 frag_read(const short* lbase, int row, int c) {
    const int pc = c ^ (row & 7);
    return *(const bf16x8*)(lbase + row * 64 + pc * 8);
}

// Split V fragment read: element e of result holds V[row][tok], tok matching
// the NATURAL post-QK P register order: slots (hi, e) <-> j_local =
// [0,1,2,3,8,9,10,11][e] + 4*hi within the 16-token chunk starting at c0*8.
// Two 8B reads: chunk c0 half hi, chunk c0+1 half hi (xor-swizzled rows).
__device__ __forceinline__ bf16x8 vsplit(const short* lbase, int row, int c0, int hi) {
    const int r7 = row & 7;
    const int pc0 = c0 ^ r7, pc1 = (c0 + 1) ^ r7;
    const unsigned* b = (const unsigned*)(lbase + row * 64);
    const int o0 = pc0 * 4 + hi * 2;   // dword offset within the 32-dword row
    const int o1 = pc1 * 4 + hi * 2;
    union { unsigned u[4]; bf16x8 v; } t;
    t.u[0] = b[o0]; t.u[1] = b[o0 + 1];
    t.u[2] = b[o1]; t.u[3] = b[o1 + 1];
    return t.v;
}

// ---------------------------------------------------------------------------
// gemm128 core: C[128x128] = A[128x384] · B[128x384]^T, both k-contig rows,
// stride CCH. BK=64 via two xor-swizzled 64x64 stage_tiles per operand
// (conflict-free frag reads), double-buffered, 6 K-iters.
// ---------------------------------------------------------------------------
__device__ __forceinline__ void gemm128_core(
    const short* __restrict__ Ag, const short* __restrict__ Bg,
    short* Ast, short* Bst, f32x4 acc[4][4])
{
    const int tid = threadIdx.x, lane = tid & 63;
    const int l15 = tid & 15, quad = (tid >> 4) & 3, wv = tid >> 6;

    stage_tile(Ag, CCH, Ast, wv, lane);
    stage_tile(Ag + 64 * CCH, CCH, Ast + 4096, wv, lane);
    stage_tile(Bg, CCH, Bst, wv, lane);
    stage_tile(Bg + 64 * CCH, CCH, Bst + 4096, wv, lane);
    __syncthreads();

#pragma unroll
    for (int kc = 0; kc < 6; ++kc) {
        const int cur = kc & 1;
        if (kc < 5) {
            short* An = Ast + (cur ^ 1) * 8192;
            short* Bn = Bst + (cur ^ 1) * 8192;
            stage_tile(Ag + (kc + 1) * 64, CCH, An, wv, lane);
            stage_tile(Ag + (kc + 1) * 64 + 64 * CCH, CCH, An + 4096, wv, lane);
            stage_tile(Bg + (kc + 1) * 64, CCH, Bn, wv, lane);
            stage_tile(Bg + (kc + 1) * 64 + 64 * CCH, CCH, Bn + 4096, wv, lane);
        }
        const short* Atile = Ast + cur * 8192 + (wv >> 1) * 4096;  // wi tile
        const short* Btile = Bst + cur * 8192 + (wv & 1) * 4096;   // wj tile
#pragma unroll
        for (int h = 0; h < 2; ++h) {
            bf16x8 a[4], b[4];
#pragma unroll
            for (int s = 0; s < 4; ++s) {
                a[s] = frag_read(Atile, s * 16 + l15, h * 4 + quad);
                b[s] = frag_read(Btile, s * 16 + l15, h * 4 + quad);
            }
#pragma unroll
            for (int si = 0; si < 4; ++si)
#pragma unroll
                for (int sj = 0; sj < 4; ++sj)
                    acc[si][sj] = MFMA16(a[si], b[sj], acc[si][sj]);
        }
        __syncthreads();
    }
}

// Epilogue: repack the 128x128 bf16 C-tile through cbuf (=Ast, free after
// the K-loop) so global stores are b128.
__device__ __forceinline__ void epilogue_bf16(
    f32x4 acc[4][4], short* cbuf,
    short* __restrict__ out, size_t obase, int ostride)
{
    const int tid = threadIdx.x;
    const int l15 = tid & 15, quad = (tid >> 4) & 3, wv = tid >> 6;
    const int wi = (wv >> 1) * 64, wj = (wv & 1) * 64;
    __syncthreads();
#pragma unroll
    for (int si = 0; si < 4; ++si)
#pragma unroll
        for (int sj = 0; sj < 4; ++sj)
#pragma unroll
            for (int rr = 0; rr < 4; ++rr)
                cbuf[(wi + si * 16 + quad * 4 + rr) * 128 + wj + sj * 16 + l15] =
                    f2b(acc[si][sj][rr]);
    __syncthreads();
#pragma unroll
    for (int pass = 0; pass < 8; ++pass) {
        const int row = pass * 16 + (tid >> 4);     // 0..127
        bf16x8 vchunk = *(const bf16x8*)(cbuf + row * 128 + l15 * 8);
        *(bf16x8*)(out + obase + (size_t)row * ostride + l15 * 8) = vchunk;
    }
}

// ---------------------------------------------------------------------------
// prep: fused transpose+convert (id<1536), weight convert (id<2112),
// amap zero (id>=2112). grid 2120.
// ---------------------------------------------------------------------------
__global__ __launch_bounds__(256) void prep(
    const float* __restrict__ Xq, const float* __restrict__ Xc,
    const float* __restrict__ w0, const float* __restrict__ w1,
    const float* __restrict__ w2, const float* __restrict__ w3,
    short* __restrict__ Xtq, short* __restrict__ Xtc,
    short* __restrict__ o0, short* __restrict__ o1,
    short* __restrict__ o2, short* __restrict__ o3,
    float* __restrict__ amap)
{
    __shared__ float tile[64][65];
    const int id = blockIdx.x, tid = threadIdx.x;
    if (id < 1536) {
        const int zz = id % 16, t = id / 16;
        const int n0 = (t % 16) * 64, c0 = (t / 16) * 64;
        const float* X = (zz < 8) ? Xq : Xc;
        short* Xt      = (zz < 8) ? Xtq : Xtc;
        const int b = zz & 7;
        const int tx = tid & 15, ty = tid >> 4;
#pragma unroll
        for (int rr = 0; rr < 4; ++rr) {
            const int c = rr * 16 + ty;
            float4 v = *(const float4*)&X[((size_t)(b * CCH + c0 + c)) * NTOK + n0 + tx * 4];
            tile[c][tx * 4 + 0] = v.x; tile[c][tx * 4 + 1] = v.y;
            tile[c][tx * 4 + 2] = v.z; tile[c][tx * 4 + 3] = v.w;
        }
        __syncthreads();
        const int n = tid >> 2, cb = (tid & 3) * 16;
        short tmp[16];
#pragma unroll
        for (int cc = 0; cc < 16; ++cc) tmp[cc] = f2b(tile[cb + cc][n]);
        short* dst = &Xt[((size_t)(b * NTOK + n0 + n)) * CCH + c0 + cb];
        *(int4*)dst = *(int4*)&tmp[0];
        *(int4*)(dst + 8) = *(int4*)&tmp[8];
    } else if (id < 2112) {
        const int w = id - 1536;
        const int which = w / 144;
        const int idx = (w % 144) * 256 + tid;
        const float* s = which == 0 ? w0 : which == 1 ? w1 : which == 2 ? w2 : w3;
        short* d       = which == 0 ? o0 : which == 1 ? o1 : which == 2 ? o2 : o3;
        float4 v = ((const float4*)s)[idx];
        short4 o = make_short4(f2b(v.x), f2b(v.y), f2b(v.z), f2b(v.w));
        ((short4*)d)[idx] = o;
    } else {
        const int o = (id - 2112) * 1024 + tid * 4;
        float4 z = {0.f, 0.f, 0.f, 0.f};
        *(float4*)&amap[o] = z;
    }
}

// ---------------------------------------------------------------------------
// Fused QKV projection, 128x128 tiles. 576 blocks: b=id%8 (XCD-local),
// r=id/8: which=r/24 (0:Q,1:K tok-major; 2:V ch-major), tt=r%24.
// Q output pre-scaled by QSCALE.
// ---------------------------------------------------------------------------
__global__ __launch_bounds__(256, 2) void gemm_qkv(
    const short* __restrict__ xtq, const short* __restrict__ xtc,
    const short* __restrict__ wq, const short* __restrict__ wk,
    const short* __restrict__ wvm,
    short* __restrict__ qout, short* __restrict__ kout, short* __restrict__ vout)
{
    __shared__ __align__(16) short Ast[2][8192];
    __shared__ __align__(16) short Bst[2][8192];
    const int id = blockIdx.x;
    const int b = id & 7, r = id >> 3;
    const int which = r / 24, tt = r % 24;

    const short *Ag, *Bg;
    short* out;
    size_t obase;
    int ostride;
    if (which < 2) {
        const int it = tt / 3, jt = tt % 3;
        const short* x = (which == 0) ? xtq : xtc;
        const short* W = (which == 0) ? wq : wk;
        Ag = x + ((size_t)(b * NTOK + it * 128)) * CCH;
        Bg = W + (size_t)(jt * 128) * CCH;
        out = (which == 0) ? qout : kout;
        obase = ((size_t)(b * NTOK + it * 128)) * CCH + jt * 128;
        ostride = CCH;
    } else {
        const int ct = tt % 3, nt = tt / 3;
        Ag = wvm + (size_t)(ct * 128) * CCH;
        Bg = xtc + ((size_t)(b * NTOK + nt * 128)) * CCH;
        out = vout;
        obase = ((size_t)(b * CCH + ct * 128)) * NTOK + nt * 128;
        ostride = NTOK;
    }

    f32x4 z4 = {0.f, 0.f, 0.f, 0.f};
    f32x4 acc[4][4];
#pragma unroll
    for (int si = 0; si < 4; ++si)
#pragma unroll
        for (int sj = 0; sj < 4; ++sj) acc[si][sj] = z4;

    gemm128_core(Ag, Bg, &Ast[0][0], &Bst[0][0], acc);

    if (which == 0) {
#pragma unroll
        for (int si = 0; si < 4; ++si)
#pragma unroll
            for (int sj = 0; sj < 4; ++sj)
#pragma unroll
                for (int rr = 0; rr < 4; ++rr)
                    acc[si][sj][rr] *= QSCALE;
    }
    epilogue_bf16(acc, &Ast[0][0], out, obase, ostride);
}

// ---------------------------------------------------------------------------
// Output projection, 128x128 tiles, fp32 out + bias. 192 blocks.
// ---------------------------------------------------------------------------
__global__ __launch_bounds__(256, 2) void o_proj(
    const short* __restrict__ wo, const short* __restrict__ omid,
    const float* __restrict__ bias, float* __restrict__ Y)
{
    __shared__ __align__(16) short Ast[2][8192];
    __shared__ __align__(16) short Bst[2][8192];
    const int id = blockIdx.x;
    const int b = id & 7, r = id >> 3;
    const int ct = r % 3, nt = r / 3;

    const short* Ag = wo + (size_t)(ct * 128) * CCH;
    const short* Bg = omid + ((size_t)(b * NTOK + nt * 128)) * CCH;

    f32x4 z4 = {0.f, 0.f, 0.f, 0.f};
    f32x4 acc[4][4];
#pragma unroll
    for (int si = 0; si < 4; ++si)
#pragma unroll
        for (int sj = 0; sj < 4; ++sj) acc[si][sj] = z4;

    gemm128_core(Ag, Bg, &Ast[0][0], &Bst[0][0], acc);

    const int tid = threadIdx.x;
    const int l15 = tid & 15, quad = (tid >> 4) & 3, wv = tid >> 6;
    const int wi = (wv >> 1) * 64, wj = (wv & 1) * 64;
#pragma unroll
    for (int si = 0; si < 4; ++si) {
#pragma unroll
        for (int rr = 0; rr < 4; ++rr) {
            const int ch = ct * 128 + wi + si * 16 + quad * 4 + rr;
            const float bv = bias[ch];
#pragma unroll
            for (int sj = 0; sj < 4; ++sj)
                Y[((size_t)(b * CCH + ch)) * NTOK + nt * 128 + wj + sj * 16 + l15] =
                    acc[si][sj][rr] + bv;
        }
    }
}

// ---------------------------------------------------------------------------
// Fused attention — SINGLE PASS, swapped-QK^T 32x32 MFMA, in-register P with
// NO cross-lane movement: the PV MFMA pairs operands physically slot-to-slot,
// so instead of redistributing P across lane halves we make the V-fragment's
// slot->token map equal P's natural one via two 8B LDS reads (vsplit).
// Unnormalized O accumulation; normalize by 1/den in epilogue.
//
// 768 blocks (b, h, 64-row i-tile). 4 waves: i_sub=(wv&1)*32, jpar=wv>>1.
// Waves with parity==jt compute tile jt; the other two stage tile jt+1.
//
// Layout facts used (HW-verified m74/m101):
//   mfma_32x32x16 C/D: col=lane&31, row=(reg&3)+8*(reg>>2)+4*(lane>>5)
// swapped QK: s = mfma(A=K, B=Q) -> lane holds S[j-regs][i=lane&31];
// s[e] has j_local = [0,1,2,3,8,9,10,11][e&7] + 4*hi + 16*(e>>3).
// ---------------------------------------------------------------------------
__global__ __launch_bounds__(256, 3) void attn(
    const short* __restrict__ qt, const short* __restrict__ kt,
    const short* __restrict__ vc, short* __restrict__ omid,
    float* __restrict__ rws)
{
    __shared__ __align__(16) short Kst[2][4096];   // 16 KB (64 tok x 64 ch)
    __shared__ __align__(16) short Vst[2][4096];   // 16 KB (64 ch x 64 tok)
    __shared__ float obuf[4][16][64];              // 16 KB epilogue combine
    __shared__ float denbuf[4][64];                // 1 KB
    __shared__ float rden_sh[2][32];

    const int tid = threadIdx.x, lane = tid & 63;
    const int l31 = lane & 31, hi = lane >> 5;
    const int wv = tid >> 6;
    const int isub = (wv & 1) * 32;
    const int jpar = wv >> 1;

    const int id = blockIdx.x;
    const int b = id & 7, rr_ = id >> 3;
    const int h = rr_ % 6, i0 = (rr_ / 6) * 64;

    const size_t hoff = (size_t)b * NTOK * CCH + h * DHEAD;
    const short* Kg = kt + hoff;                                   // stride CCH
    const short* Vg = vc + ((size_t)(b * CCH + h * DHEAD)) * NTOK; // stride NTOK

    // Q B-frags hoisted: lane holds Q[i = i0+isub+l31, d = m*16 + hi*8 ..+8]
    const short* qp = qt + hoff + (size_t)(i0 + isub + l31) * CCH + hi * 8;
    bf16x8 qf[4];
#pragma unroll
    for (int m = 0; m < 4; ++m) qf[m] = *(const bf16x8*)(qp + m * 16);

    // prologue: all 4 waves stage tile 0
    stage_tile(Kg, CCH, Kst[0], wv, lane);
    stage_tile(Vg, NTOK, Vst[0], wv, lane);
    __syncthreads();

    const f32x16 z16 = {0,0,0,0,0,0,0,0,0,0,0,0,0,0,0,0};
    f32x16 oacc0 = z16, oacc1 = z16;   // d 0..31 / 32..63
    float den = 0.f;

    for (int jt = 0; jt < 16; ++jt) {
        const int cur = jt & 1;
        if ((jt & 1) == jpar) {
            const short* Kb = Kst[cur];
            const short* Vb = Vst[cur];
#pragma unroll
            for (int jsub = 0; jsub < 2; ++jsub) {
                f32x16 s = z16;
#pragma unroll
                for (int m = 0; m < 4; ++m)
                    s = MFMA32(frag_read(Kb, jsub * 32 + l31, 2 * m + hi), qf[m], s);
                // e = exp2(s); per-lane den accum; natural reg order IS the
                // A-frag element order (V side matches via vsplit).
                bf16x8 pa0, pa1;
#pragma unroll
                for (int e = 0; e < 8; ++e) {
                    const float x0 = EXP2(s[e]);
                    const float x1 = EXP2(s[8 + e]);
                    den += x0 + x1;
                    pa0[e] = (__bf16)x0;
                    pa1[e] = (__bf16)x1;
                }
                oacc0 = MFMA32(pa0, vsplit(Vb, l31,      jsub * 4,     hi), oacc0);
                oacc0 = MFMA32(pa1, vsplit(Vb, l31,      jsub * 4 + 2, hi), oacc0);
                oacc1 = MFMA32(pa0, vsplit(Vb, 32 + l31, jsub * 4,     hi), oacc1);
                oacc1 = MFMA32(pa1, vsplit(Vb, 32 + l31, jsub * 4 + 2, hi), oacc1);
            }
        } else if (jt < 15) {
            // this wave's next tile is jt+1 — stage it while others compute
            const int sw = wv & 1;
            stage_tile_2w(Kg + (size_t)(jt + 1) * 64 * CCH, CCH, Kst[cur ^ 1], sw, lane);
            stage_tile_2w(Vg + (size_t)(jt + 1) * 64, NTOK, Vst[cur ^ 1], sw, lane);
        }
        __syncthreads();
    }

    // ---- epilogue: cross-parity combine, normalize, store ----
    const int dh = jpar;               // this wave finalizes d-half dh
    if (dh == 0) {
#pragma unroll
        for (int g2 = 0; g2 < 16; ++g2) obuf[wv][g2][lane] = oacc1[g2];
    } else {
#pragma unroll
        for (int g2 = 0; g2 < 16; ++g2) obuf[wv][g2][lane] = oacc0[g2];
    }
    denbuf[wv][lane] = den;
    __syncthreads();

    const int g = wv & 1;
    const float dtot = denbuf[g][l31] + denbuf[g][l31 + 32]
                     + denbuf[g | 2][l31] + denbuf[g | 2][l31 + 32];
    const float rden = 1.0f / dtot;
    if (wv < 2 && lane < 32) {
        rws[((b * 6 + h) << 10) + i0 + isub + lane] = rden;
        rden_sh[wv][lane] = rden;
    }
    __syncthreads();

#pragma unroll
    for (int reg = 0; reg < 16; ++reg) {
        const int crw = (reg & 3) + 8 * (reg >> 2) + 4 * hi;     // i-local 0..31
        const float rd = rden_sh[g][crw];
        const float okeep = (dh == 0) ? oacc0[reg] : oacc1[reg];
        const float ov = (okeep + obuf[wv ^ 2][reg][lane]) * rd;
        omid[((size_t)(b * NTOK + i0 + isub + crw)) * CCH + h * DHEAD + dh * 32 + l31] =
            f2b(ov);
    }
}

// ---------------------------------------------------------------------------
// amap kernel: recompute S = QK^T (non-swapped 16x16 path: i lives in reg
// dims -> colsum is 3 adds + 2 shuffles), p = exp2(s)*rden[i], column-sum,
// atomic into amap. 768 blocks. This is the old verified pass-2 structure
// minus PV minus P-packing.
// ---------------------------------------------------------------------------
__global__ __launch_bounds__(256) void amap_k(
    const short* __restrict__ qt, const short* __restrict__ kt,
    const float* __restrict__ rws, float* __restrict__ amap)
{
    __shared__ __align__(16) short Kst[2][4096];
    __shared__ float colbuf[2][4][64];

    const int tid = threadIdx.x, lane = tid & 63;
    const int l15 = tid & 15, quad = (tid >> 4) & 3, wv = tid >> 6;
    const int id = blockIdx.x;
    const int b = id & 7, rr_ = id >> 3;
    const int h = rr_ % 6, i0 = (rr_ / 6) * 64;

    const size_t hoff = (size_t)b * NTOK * CCH + h * DHEAD;
    const short* Kg = kt + hoff;
    const short* qp = qt + hoff + (size_t)(i0 + wv * 16 + l15) * CCH + quad * 8;
    const bf16x8 qa0 = *(const bf16x8*)qp;
    const bf16x8 qa1 = *(const bf16x8*)(qp + 32);

    float rdl[4];
#pragma unroll
    for (int r = 0; r < 4; ++r)
        rdl[r] = rws[((b * 6 + h) << 10) + i0 + wv * 16 + quad * 4 + r];

    stage_tile(Kg, CCH, Kst[0], wv, lane);
    __syncthreads();

    for (int jt = 0; jt < 16; ++jt) {
        const int cur = jt & 1;
        if (jt < 15)
            stage_tile(Kg + (size_t)(jt + 1) * 64 * CCH, CCH, Kst[cur ^ 1], wv, lane);
        f32x4 z4 = {0.f, 0.f, 0.f, 0.f};
        f32x4 s[4] = {z4, z4, z4, z4};
#pragma unroll
        for (int ns = 0; ns < 4; ++ns) {
            const int row = ns * 16 + l15;
            bf16x8 k0 = frag_read(Kst[cur], row, quad);
            bf16x8 k1 = frag_read(Kst[cur], row, quad + 4);
            s[ns] = MFMA16(qa0, k0, s[ns]);
            s[ns] = MFMA16(qa1, k1, s[ns]);
        }
#pragma unroll
        for (int ns = 0; ns < 4; ++ns) {
            float cs = EXP2(s[ns][0]) * rdl[0] + EXP2(s[ns][1]) * rdl[1]
                     + EXP2(s[ns][2]) * rdl[2] + EXP2(s[ns][3]) * rdl[3];
            cs += __shfl_xor(cs, 16);
            cs += __shfl_xor(cs, 32);
            if (quad == 0) colbuf[cur][wv][ns * 16 + l15] = cs;
        }
        __syncthreads();
        if (tid < 64) {
            const float t = colbuf[cur][0][tid] + colbuf[cur][1][tid]
                          + colbuf[cur][2][tid] + colbuf[cur][3][tid];
            atomicAdd(amap + (size_t)b * NTOK + jt * 64 + tid,
                      t * (1.0f / (HEADS * NTOK)));
        }
    }
}

// ---------------------------------------------------------------------------
extern "C" void kernel_launch(void* const* d_in, const int* in_sizes, int n_in,
                              void* d_out, int out_size, void* d_ws, size_t ws_size,
                              hipStream_t stream)
{
    const float* query   = (const float*)d_in[0];
    const float* context = (const float*)d_in[1];
    const float* Wq      = (const float*)d_in[2];
    const float* Wk      = (const float*)d_in[3];
    const float* Wv      = (const float*)d_in[4];
    const float* Wo      = (const float*)d_in[5];
    const float* bo      = (const float*)d_in[6];

    float* out = (float*)d_out;                          // [8,384,1024] fp32
    const size_t out_elems = (size_t)BATCH * CCH * NTOK;
    float* attn_map = out + out_elems;                   // [8,1024] fp32

    short* ws = (short*)d_ws;
    const size_t XT = (size_t)BATCH * NTOK * CCH;
    const size_t WSZ = (size_t)CCH * CCH;
    short* xtq  = ws;
    short* xtc  = xtq + XT;
    short* wqb  = xtc + XT;
    short* wkb  = wqb + WSZ;
    short* wvb  = wkb + WSZ;
    short* wob  = wvb + WSZ;
    short* qtb  = wob + WSZ;
    short* ktb  = qtb + XT;
    short* vcb  = ktb + XT;
    short* omid = vcb + XT;
    float* rws  = (float*)(omid + XT);                   // [8*6*1024] fp32 rden

    const dim3 blk(256);

    prep<<<dim3(2120), blk, 0, stream>>>(query, context, Wq, Wk, Wv, Wo,
                                         xtq, xtc, wqb, wkb, wvb, wob, attn_map);

    gemm_qkv<<<dim3(576), blk, 0, stream>>>(xtq, xtc, wqb, wkb, wvb,
                                            qtb, ktb, vcb);

    attn<<<dim3(768), blk, 0, stream>>>(qtb, ktb, vcb, omid, rws);

    amap_k<<<dim3(768), blk, 0, stream>>>(qtb, ktb, rws, attn_map);

    o_proj<<<dim3(192), blk, 0, stream>>>(wob, omid, bo, out);
}

// Round 4
// 154.745 us; speedup vs baseline: 1.0917x; 1.0216x over previous
//
#include <hip/hip_runtime.h>

// Problem constants
#define BATCH 8
#define CCH   384      // channels C == INNER
#define NTOK  1024     // H*W
#define HEADS 6
#define DHEAD 64
// softmax scale 1/8 and log2(e) folded into Q at projection time:
// qout = Q * 0.125 * 1.4426950408889634, attn uses exp2(s) = bare v_exp.
#define QSCALE 0.18033688011112042f

typedef __bf16 bf16x8 __attribute__((ext_vector_type(8)));
typedef float  f32x4  __attribute__((ext_vector_type(4)));
typedef float  f32x16 __attribute__((ext_vector_type(16)));

#define MFMA16(a, b, c) __builtin_amdgcn_mfma_f32_16x16x32_bf16((a), (b), (c), 0, 0, 0)
#define MFMA32(a, b, c) __builtin_amdgcn_mfma_f32_32x32x16_bf16((a), (b), (c), 0, 0, 0)
#define EXP2(x) __builtin_amdgcn_exp2f(x)

// fp32 -> bf16 RNE, raw bits
__device__ __forceinline__ short f2b(float x) {
    unsigned u = __float_as_uint(x);
    u += 0x7fffu + ((u >> 16) & 1u);
    return (short)(u >> 16);
}

// async global->LDS, 16B/lane. LDS dst = wave-uniform base + lane*16.
__device__ __forceinline__ void gld_lds16(const short* gp, short* lp) {
    __builtin_amdgcn_global_load_lds(
        (const __attribute__((address_space(1))) void*)gp,
        (__attribute__((address_space(3))) void*)lp, 16, 0, 0);
}

// ---- 64x64 xor-swizzled tile staging (4 waves) — verified r3/r4 ----
__device__ __forceinline__ void stage_tile(const short* gbase, size_t gstride,
                                           short* lbase, int wv, int lane) {
#pragma unroll
    for (int t = 0; t < 2; ++t) {
        const int row = t * 8 + (lane >> 3);
        const int c   = (lane & 7) ^ (row & 7);
        gld_lds16(gbase + (size_t)(wv * 16 + row) * gstride + c * 8,
                  lbase + (wv * 16 + t * 8) * 64);
    }
}
// same tile, staged by 2 waves (sw = 0/1), 4 gld per thread
__device__ __forceinline__ void stage_tile_2w(const short* gbase, size_t gstride,
                                              short* lbase, int sw, int lane) {
#pragma unroll
    for (int t = 0; t < 4; ++t) {
        const int row = sw * 32 + t * 8 + (lane >> 3);
        const int c   = (lane & 7) ^ (row & 7);
        gld_lds16(gbase + (size_t)row * gstride + c * 8,
                  lbase + (sw * 32 + t * 8) * 64);
    }
}
__device__ __forceinline__ bf16x8 frag_read(const short* lbase, int row, int c) {
    const int pc = c ^ (row & 7);
    return *(const bf16x8*)(lbase + row * 64 + pc * 8);
}

// Split V fragment read: element e of result holds V[row][tok], tok matching
// the NATURAL post-QK P register order: slots (hi, e) <-> j_local =
// [0,1,2,3,8,9,10,11][e] + 4*hi within the 16-token chunk starting at c0*8.
// Two 8B reads: chunk c0 half hi, chunk c0+1 half hi (xor-swizzled rows).
__device__ __forceinline__ bf16x8 vsplit(const short* lbase, int row, int c0, int hi) {
    const int r7 = row & 7;
    const int pc0 = c0 ^ r7, pc1 = (c0 + 1) ^ r7;
    const unsigned* b = (const unsigned*)(lbase + row * 64);
    const int o0 = pc0 * 4 + hi * 2;   // dword offset within the 32-dword row
    const int o1 = pc1 * 4 + hi * 2;
    union { unsigned u[4]; bf16x8 v; } t;
    t.u[0] = b[o0]; t.u[1] = b[o0 + 1];
    t.u[2] = b[o1]; t.u[3] = b[o1 + 1];
    return t.v;
}

// ---------------------------------------------------------------------------
// gemm128 core: C[128x128] = A[128x384] · B[128x384]^T, both k-contig rows,
// stride CCH. BK=64 via two xor-swizzled 64x64 stage_tiles per operand
// (conflict-free frag reads), double-buffered, 6 K-iters.
// ---------------------------------------------------------------------------
__device__ __forceinline__ void gemm128_core(
    const short* __restrict__ Ag, const short* __restrict__ Bg,
    short* Ast, short* Bst, f32x4 acc[4][4])
{
    const int tid = threadIdx.x, lane = tid & 63;
    const int l15 = tid & 15, quad = (tid >> 4) & 3, wv = tid >> 6;

    stage_tile(Ag, CCH, Ast, wv, lane);
    stage_tile(Ag + 64 * CCH, CCH, Ast + 4096, wv, lane);
    stage_tile(Bg, CCH, Bst, wv, lane);
    stage_tile(Bg + 64 * CCH, CCH, Bst + 4096, wv, lane);
    __syncthreads();

#pragma unroll
    for (int kc = 0; kc < 6; ++kc) {
        const int cur = kc & 1;
        if (kc < 5) {
            short* An = Ast + (cur ^ 1) * 8192;
            short* Bn = Bst + (cur ^ 1) * 8192;
            stage_tile(Ag + (kc + 1) * 64, CCH, An, wv, lane);
            stage_tile(Ag + (kc + 1) * 64 + 64 * CCH, CCH, An + 4096, wv, lane);
            stage_tile(Bg + (kc + 1) * 64, CCH, Bn, wv, lane);
            stage_tile(Bg + (kc + 1) * 64 + 64 * CCH, CCH, Bn + 4096, wv, lane);
        }
        const short* Atile = Ast + cur * 8192 + (wv >> 1) * 4096;  // wi tile
        const short* Btile = Bst + cur * 8192 + (wv & 1) * 4096;   // wj tile
#pragma unroll
        for (int h = 0; h < 2; ++h) {
            bf16x8 a[4], b[4];
#pragma unroll
            for (int s = 0; s < 4; ++s) {
                a[s] = frag_read(Atile, s * 16 + l15, h * 4 + quad);
                b[s] = frag_read(Btile, s * 16 + l15, h * 4 + quad);
            }
#pragma unroll
            for (int si = 0; si < 4; ++si)
#pragma unroll
                for (int sj = 0; sj < 4; ++sj)
                    acc[si][sj] = MFMA16(a[si], b[sj], acc[si][sj]);
        }
        __syncthreads();
    }
}

// Epilogue: repack the 128x128 bf16 C-tile through cbuf (=Ast, free after
// the K-loop) so global stores are b128.
__device__ __forceinline__ void epilogue_bf16(
    f32x4 acc[4][4], short* cbuf,
    short* __restrict__ out, size_t obase, int ostride)
{
    const int tid = threadIdx.x;
    const int l15 = tid & 15, quad = (tid >> 4) & 3, wv = tid >> 6;
    const int wi = (wv >> 1) * 64, wj = (wv & 1) * 64;
    __syncthreads();
#pragma unroll
    for (int si = 0; si < 4; ++si)
#pragma unroll
        for (int sj = 0; sj < 4; ++sj)
#pragma unroll
            for (int rr = 0; rr < 4; ++rr)
                cbuf[(wi + si * 16 + quad * 4 + rr) * 128 + wj + sj * 16 + l15] =
                    f2b(acc[si][sj][rr]);
    __syncthreads();
#pragma unroll
    for (int pass = 0; pass < 8; ++pass) {
        const int row = pass * 16 + (tid >> 4);     // 0..127
        bf16x8 vchunk = *(const bf16x8*)(cbuf + row * 128 + l15 * 8);
        *(bf16x8*)(out + obase + (size_t)row * ostride + l15 * 8) = vchunk;
    }
}

// ---------------------------------------------------------------------------
// prep: fused transpose+convert (id<1536), weight convert (id<2112),
// amap zero (id>=2112). grid 2120.
// ---------------------------------------------------------------------------
__global__ __launch_bounds__(256) void prep(
    const float* __restrict__ Xq, const float* __restrict__ Xc,
    const float* __restrict__ w0, const float* __restrict__ w1,
    const float* __restrict__ w2, const float* __restrict__ w3,
    short* __restrict__ Xtq, short* __restrict__ Xtc,
    short* __restrict__ o0, short* __restrict__ o1,
    short* __restrict__ o2, short* __restrict__ o3,
    float* __restrict__ amap)
{
    __shared__ float tile[64][65];
    const int id = blockIdx.x, tid = threadIdx.x;
    if (id < 1536) {
        const int zz = id % 16, t = id / 16;
        const int n0 = (t % 16) * 64, c0 = (t / 16) * 64;
        const float* X = (zz < 8) ? Xq : Xc;
        short* Xt      = (zz < 8) ? Xtq : Xtc;
        const int b = zz & 7;
        const int tx = tid & 15, ty = tid >> 4;
#pragma unroll
        for (int rr = 0; rr < 4; ++rr) {
            const int c = rr * 16 + ty;
            float4 v = *(const float4*)&X[((size_t)(b * CCH + c0 + c)) * NTOK + n0 + tx * 4];
            tile[c][tx * 4 + 0] = v.x; tile[c][tx * 4 + 1] = v.y;
            tile[c][tx * 4 + 2] = v.z; tile[c][tx * 4 + 3] = v.w;
        }
        __syncthreads();
        const int n = tid >> 2, cb = (tid & 3) * 16;
        short tmp[16];
#pragma unroll
        for (int cc = 0; cc < 16; ++cc) tmp[cc] = f2b(tile[cb + cc][n]);
        short* dst = &Xt[((size_t)(b * NTOK + n0 + n)) * CCH + c0 + cb];
        *(int4*)dst = *(int4*)&tmp[0];
        *(int4*)(dst + 8) = *(int4*)&tmp[8];
    } else if (id < 2112) {
        const int w = id - 1536;
        const int which = w / 144;
        const int idx = (w % 144) * 256 + tid;
        const float* s = which == 0 ? w0 : which == 1 ? w1 : which == 2 ? w2 : w3;
        short* d       = which == 0 ? o0 : which == 1 ? o1 : which == 2 ? o2 : o3;
        float4 v = ((const float4*)s)[idx];
        short4 o = make_short4(f2b(v.x), f2b(v.y), f2b(v.z), f2b(v.w));
        ((short4*)d)[idx] = o;
    } else {
        const int o = (id - 2112) * 1024 + tid * 4;
        float4 z = {0.f, 0.f, 0.f, 0.f};
        *(float4*)&amap[o] = z;
    }
}

// ---------------------------------------------------------------------------
// Fused QKV projection, 128x128 tiles. 576 blocks: b=id%8 (XCD-local),
// r=id/8: which=r/24 (0:Q,1:K tok-major; 2:V ch-major), tt=r%24.
// Q output pre-scaled by QSCALE.
// ---------------------------------------------------------------------------
__global__ __launch_bounds__(256, 2) void gemm_qkv(
    const short* __restrict__ xtq, const short* __restrict__ xtc,
    const short* __restrict__ wq, const short* __restrict__ wk,
    const short* __restrict__ wvm,
    short* __restrict__ qout, short* __restrict__ kout, short* __restrict__ vout)
{
    __shared__ __align__(16) short Ast[2][8192];
    __shared__ __align__(16) short Bst[2][8192];
    const int id = blockIdx.x;
    const int b = id & 7, r = id >> 3;
    const int which = r / 24, tt = r % 24;

    const short *Ag, *Bg;
    short* out;
    size_t obase;
    int ostride;
    if (which < 2) {
        const int it = tt / 3, jt = tt % 3;
        const short* x = (which == 0) ? xtq : xtc;
        const short* W = (which == 0) ? wq : wk;
        Ag = x + ((size_t)(b * NTOK + it * 128)) * CCH;
        Bg = W + (size_t)(jt * 128) * CCH;
        out = (which == 0) ? qout : kout;
        obase = ((size_t)(b * NTOK + it * 128)) * CCH + jt * 128;
        ostride = CCH;
    } else {
        const int ct = tt % 3, nt = tt / 3;
        Ag = wvm + (size_t)(ct * 128) * CCH;
        Bg = xtc + ((size_t)(b * NTOK + nt * 128)) * CCH;
        out = vout;
        obase = ((size_t)(b * CCH + ct * 128)) * NTOK + nt * 128;
        ostride = NTOK;
    }

    f32x4 z4 = {0.f, 0.f, 0.f, 0.f};
    f32x4 acc[4][4];
#pragma unroll
    for (int si = 0; si < 4; ++si)
#pragma unroll
        for (int sj = 0; sj < 4; ++sj) acc[si][sj] = z4;

    gemm128_core(Ag, Bg, &Ast[0][0], &Bst[0][0], acc);

    if (which == 0) {
#pragma unroll
        for (int si = 0; si < 4; ++si)
#pragma unroll
            for (int sj = 0; sj < 4; ++sj)
#pragma unroll
                for (int rr = 0; rr < 4; ++rr)
                    acc[si][sj][rr] *= QSCALE;
    }
    epilogue_bf16(acc, &Ast[0][0], out, obase, ostride);
}

// ---------------------------------------------------------------------------
// Output projection, 128x128 tiles, fp32 out + bias. 192 blocks.
// ---------------------------------------------------------------------------
__global__ __launch_bounds__(256, 2) void o_proj(
    const short* __restrict__ wo, const short* __restrict__ omid,
    const float* __restrict__ bias, float* __restrict__ Y)
{
    __shared__ __align__(16) short Ast[2][8192];
    __shared__ __align__(16) short Bst[2][8192];
    const int id = blockIdx.x;
    const int b = id & 7, r = id >> 3;
    const int ct = r % 3, nt = r / 3;

    const short* Ag = wo + (size_t)(ct * 128) * CCH;
    const short* Bg = omid + ((size_t)(b * NTOK + nt * 128)) * CCH;

    f32x4 z4 = {0.f, 0.f, 0.f, 0.f};
    f32x4 acc[4][4];
#pragma unroll
    for (int si = 0; si < 4; ++si)
#pragma unroll
        for (int sj = 0; sj < 4; ++sj) acc[si][sj] = z4;

    gemm128_core(Ag, Bg, &Ast[0][0], &Bst[0][0], acc);

    const int tid = threadIdx.x;
    const int l15 = tid & 15, quad = (tid >> 4) & 3, wv = tid >> 6;
    const int wi = (wv >> 1) * 64, wj = (wv & 1) * 64;
#pragma unroll
    for (int si = 0; si < 4; ++si) {
#pragma unroll
        for (int rr = 0; rr < 4; ++rr) {
            const int ch = ct * 128 + wi + si * 16 + quad * 4 + rr;
            const float bv = bias[ch];
#pragma unroll
            for (int sj = 0; sj < 4; ++sj)
                Y[((size_t)(b * CCH + ch)) * NTOK + nt * 128 + wj + sj * 16 + l15] =
                    acc[si][sj][rr] + bv;
        }
    }
}

// ---------------------------------------------------------------------------
// Fused attention + amap — single pass, swapped-QK^T 32x32 MFMA, in-register
// P (vsplit operand pairing, verified r2). jsub-split schedule: ALL 4 waves
// compute EVERY tile; wave = (isub = (wv&1)*32, js = wv>>1) computes its
// fixed jsub half while waves js=0 stage next-K and js=1 stage next-V
// BEFORE their compute (staging latency hides under MFMA+exp).
// den/oacc wave semantics identical to the verified r2 parity version
// (same bit assignment), so the epilogue is unchanged.
// Tail: amap via the verified amap_k body (16x16 layout, cheap colsum) on
// L2-hot K, using rden from LDS. 768 blocks = exactly 3/CU, one residency
// wave, no tail effect.
// ---------------------------------------------------------------------------
__global__ __launch_bounds__(256, 3) void attn(
    const short* __restrict__ qt, const short* __restrict__ kt,
    const short* __restrict__ vc, short* __restrict__ omid,
    float* __restrict__ amap)
{
    __shared__ __align__(16) short Kst[2][4096];   // 16 KB (64 tok x 64 ch)
    __shared__ __align__(16) short Vst[2][4096];   // 16 KB (64 ch x 64 tok)
    __shared__ float obuf[4][16][64];              // 16 KB epilogue combine
    __shared__ float denbuf[4][64];                // 1 KB
    __shared__ float rden_sh[2][32];
    __shared__ float colbuf[2][4][64];             // 2 KB (amap tail)

    const int tid = threadIdx.x, lane = tid & 63;
    const int l31 = lane & 31, hi = lane >> 5;
    const int wv = tid >> 6;
    const int isub = (wv & 1) * 32;
    const int js = wv >> 1;            // this wave's fixed jsub

    const int id = blockIdx.x;
    const int b = id & 7, rr_ = id >> 3;
    const int h = rr_ % 6, i0 = (rr_ / 6) * 64;

    const size_t hoff = (size_t)b * NTOK * CCH + h * DHEAD;
    const short* Kg = kt + hoff;                                   // stride CCH
    const short* Vg = vc + ((size_t)(b * CCH + h * DHEAD)) * NTOK; // stride NTOK

    // Q B-frags hoisted: lane holds Q[i = i0+isub+l31, d = m*16 + hi*8 ..+8]
    const short* qp = qt + hoff + (size_t)(i0 + isub + l31) * CCH + hi * 8;
    bf16x8 qf[4];
#pragma unroll
    for (int m = 0; m < 4; ++m) qf[m] = *(const bf16x8*)(qp + m * 16);

    // prologue: all 4 waves stage tile 0 (K and V)
    stage_tile(Kg, CCH, Kst[0], wv, lane);
    stage_tile(Vg, NTOK, Vst[0], wv, lane);
    __syncthreads();

    const f32x16 z16 = {0,0,0,0,0,0,0,0,0,0,0,0,0,0,0,0};
    f32x16 oacc0 = z16, oacc1 = z16;   // d 0..31 / 32..63
    float den = 0.f;

    for (int jt = 0; jt < 16; ++jt) {
        const int cur = jt & 1;
        // stage next tile first: js=0 waves bring K, js=1 waves bring V.
        if (jt < 15) {
            if (js == 0)
                stage_tile_2w(Kg + (size_t)(jt + 1) * 64 * CCH, CCH,
                              Kst[cur ^ 1], wv & 1, lane);
            else
                stage_tile_2w(Vg + (size_t)(jt + 1) * 64, NTOK,
                              Vst[cur ^ 1], wv & 1, lane);
        }
        // compute this wave's jsub on the current tile
        {
            const short* Kb = Kst[cur];
            const short* Vb = Vst[cur];
            f32x16 s = z16;
#pragma unroll
            for (int m = 0; m < 4; ++m)
                s = MFMA32(frag_read(Kb, js * 32 + l31, 2 * m + hi), qf[m], s);
            bf16x8 pa0, pa1;
#pragma unroll
            for (int e = 0; e < 8; ++e) {
                const float x0 = EXP2(s[e]);
                const float x1 = EXP2(s[8 + e]);
                den += x0 + x1;
                pa0[e] = (__bf16)x0;
                pa1[e] = (__bf16)x1;
            }
            oacc0 = MFMA32(pa0, vsplit(Vb, l31,      js * 4,     hi), oacc0);
            oacc0 = MFMA32(pa1, vsplit(Vb, l31,      js * 4 + 2, hi), oacc0);
            oacc1 = MFMA32(pa0, vsplit(Vb, 32 + l31, js * 4,     hi), oacc1);
            oacc1 = MFMA32(pa1, vsplit(Vb, 32 + l31, js * 4 + 2, hi), oacc1);
        }
        __syncthreads();
    }

    // ---- epilogue: cross-js combine, normalize, store (verified r2) ----
    const int dh = js;                 // this wave finalizes d-half dh
    if (dh == 0) {
#pragma unroll
        for (int g2 = 0; g2 < 16; ++g2) obuf[wv][g2][lane] = oacc1[g2];
    } else {
#pragma unroll
        for (int g2 = 0; g2 < 16; ++g2) obuf[wv][g2][lane] = oacc0[g2];
    }
    denbuf[wv][lane] = den;
    __syncthreads();

    const int g = wv & 1;
    const float dtot = denbuf[g][l31] + denbuf[g][l31 + 32]
                     + denbuf[g | 2][l31] + denbuf[g | 2][l31 + 32];
    const float rden = 1.0f / dtot;
    if (wv < 2 && lane < 32)
        rden_sh[wv][lane] = rden;
    __syncthreads();

#pragma unroll
    for (int reg = 0; reg < 16; ++reg) {
        const int crw = (reg & 3) + 8 * (reg >> 2) + 4 * hi;     // i-local 0..31
        const float rd = rden_sh[g][crw];
        const float okeep = (dh == 0) ? oacc0[reg] : oacc1[reg];
        const float ov = (okeep + obuf[wv ^ 2][reg][lane]) * rd;
        omid[((size_t)(b * NTOK + i0 + isub + crw)) * CCH + h * DHEAD + dh * 32 + l31] =
            f2b(ov);
    }

    // ---- amap tail (verified amap_k body; K is L2-hot, rden from LDS) ----
    const int l15 = tid & 15, quad = (tid >> 4) & 3;
    const short* qp2 = qt + hoff + (size_t)(i0 + wv * 16 + l15) * CCH + quad * 8;
    const bf16x8 qa0 = *(const bf16x8*)qp2;
    const bf16x8 qa1 = *(const bf16x8*)(qp2 + 32);

    float rdl[4];
#pragma unroll
    for (int r = 0; r < 4; ++r) {
        const int row = wv * 16 + quad * 4 + r;                  // 0..63
        rdl[r] = rden_sh[row >> 5][row & 31];
    }

    stage_tile(Kg, CCH, Kst[0], wv, lane);
    __syncthreads();

    for (int jt = 0; jt < 16; ++jt) {
        const int cur = jt & 1;
        if (jt < 15)
            stage_tile(Kg + (size_t)(jt + 1) * 64 * CCH, CCH, Kst[cur ^ 1], wv, lane);
        f32x4 z4 = {0.f, 0.f, 0.f, 0.f};
        f32x4 s[4] = {z4, z4, z4, z4};
#pragma unroll
        for (int ns = 0; ns < 4; ++ns) {
            const int row = ns * 16 + l15;
            bf16x8 k0 = frag_read(Kst[cur], row, quad);
            bf16x8 k1 = frag_read(Kst[cur], row, quad + 4);
            s[ns] = MFMA16(qa0, k0, s[ns]);
            s[ns] = MFMA16(qa1, k1, s[ns]);
        }
#pragma unroll
        for (int ns = 0; ns < 4; ++ns) {
            float cs = EXP2(s[ns][0]) * rdl[0] + EXP2(s[ns][1]) * rdl[1]
                     + EXP2(s[ns][2]) * rdl[2] + EXP2(s[ns][3]) * rdl[3];
            cs += __shfl_xor(cs, 16);
            cs += __shfl_xor(cs, 32);
            if (quad == 0) colbuf[cur][wv][ns * 16 + l15] = cs;
        }
        __syncthreads();
        if (tid < 64) {
            const float t = colbuf[cur][0][tid] + colbuf[cur][1][tid]
                          + colbuf[cur][2][tid] + colbuf[cur][3][tid];
            atomicAdd(amap + (size_t)b * NTOK + jt * 64 + tid,
                      t * (1.0f / (HEADS * NTOK)));
        }
    }
}

// ---------------------------------------------------------------------------
extern "C" void kernel_launch(void* const* d_in, const int* in_sizes, int n_in,
                              void* d_out, int out_size, void* d_ws, size_t ws_size,
                              hipStream_t stream)
{
    const float* query   = (const float*)d_in[0];
    const float* context = (const float*)d_in[1];
    const float* Wq      = (const float*)d_in[2];
    const float* Wk      = (const float*)d_in[3];
    const float* Wv      = (const float*)d_in[4];
    const float* Wo      = (const float*)d_in[5];
    const float* bo      = (const float*)d_in[6];

    float* out = (float*)d_out;                          // [8,384,1024] fp32
    const size_t out_elems = (size_t)BATCH * CCH * NTOK;
    float* attn_map = out + out_elems;                   // [8,1024] fp32

    short* ws = (short*)d_ws;
    const size_t XT = (size_t)BATCH * NTOK * CCH;
    const size_t WSZ = (size_t)CCH * CCH;
    short* xtq  = ws;
    short* xtc  = xtq + XT;
    short* wqb  = xtc + XT;
    short* wkb  = wqb + WSZ;
    short* wvb  = wkb + WSZ;
    short* wob  = wvb + WSZ;
    short* qtb  = wob + WSZ;
    short* ktb  = qtb + XT;
    short* vcb  = ktb + XT;
    short* omid = vcb + XT;

    const dim3 blk(256);

    prep<<<dim3(2120), blk, 0, stream>>>(query, context, Wq, Wk, Wv, Wo,
                                         xtq, xtc, wqb, wkb, wvb, wob, attn_map);

    gemm_qkv<<<dim3(576), blk, 0, stream>>>(xtq, xtc, wqb, wkb, wvb,
                                            qtb, ktb, vcb);

    attn<<<dim3(768), blk, 0, stream>>>(qtb, ktb, vcb, omid, attn_map);

    o_proj<<<dim3(192), blk, 0, stream>>>(wob, omid, bo, out);
}

// Round 5
// 145.877 us; speedup vs baseline: 1.1581x; 1.0608x over previous
//
#include <hip/hip_runtime.h>

// Problem constants
#define BATCH 8
#define CCH   384      // channels C == INNER
#define NTOK  1024     // H*W
#define HEADS 6
#define DHEAD 64
// softmax scale 1/8 and log2(e) folded into Q at projection time:
// qout = Q * 0.125 * 1.4426950408889634, attn uses exp2(s) = bare v_exp.
#define QSCALE 0.18033688011112042f

typedef __bf16 bf16x8 __attribute__((ext_vector_type(8)));
typedef float  f32x4  __attribute__((ext_vector_type(4)));
typedef float  f32x16 __attribute__((ext_vector_type(16)));

#define MFMA16(a, b, c) __builtin_amdgcn_mfma_f32_16x16x32_bf16((a), (b), (c), 0, 0, 0)
#define MFMA32(a, b, c) __builtin_amdgcn_mfma_f32_32x32x16_bf16((a), (b), (c), 0, 0, 0)
#define EXP2(x) __builtin_amdgcn_exp2f(x)

// fp32 -> bf16 RNE, raw bits
__device__ __forceinline__ short f2b(float x) {
    unsigned u = __float_as_uint(x);
    u += 0x7fffu + ((u >> 16) & 1u);
    return (short)(u >> 16);
}

// async global->LDS, 16B/lane. LDS dst = wave-uniform base + lane*16.
__device__ __forceinline__ void gld_lds16(const short* gp, short* lp) {
    __builtin_amdgcn_global_load_lds(
        (const __attribute__((address_space(1))) void*)gp,
        (__attribute__((address_space(3))) void*)lp, 16, 0, 0);
}

// ---- 64x64 xor-swizzled tile staging (4 waves) — verified r3/r4 ----
__device__ __forceinline__ void stage_tile(const short* gbase, size_t gstride,
                                           short* lbase, int wv, int lane) {
#pragma unroll
    for (int t = 0; t < 2; ++t) {
        const int row = t * 8 + (lane >> 3);
        const int c   = (lane & 7) ^ (row & 7);
        gld_lds16(gbase + (size_t)(wv * 16 + row) * gstride + c * 8,
                  lbase + (wv * 16 + t * 8) * 64);
    }
}
// same tile, staged by 2 waves (sw = 0/1), 4 gld per thread
__device__ __forceinline__ void stage_tile_2w(const short* gbase, size_t gstride,
                                              short* lbase, int sw, int lane) {
#pragma unroll
    for (int t = 0; t < 4; ++t) {
        const int row = sw * 32 + t * 8 + (lane >> 3);
        const int c   = (lane & 7) ^ (row & 7);
        gld_lds16(gbase + (size_t)row * gstride + c * 8,
                  lbase + (sw * 32 + t * 8) * 64);
    }
}
__device__ __forceinline__ bf16x8 frag_read(const short* lbase, int row, int c) {
    const int pc = c ^ (row & 7);
    return *(const bf16x8*)(lbase + row * 64 + pc * 8);
}

// Split V fragment read: element e of result holds V[row][tok], tok matching
// the NATURAL post-QK P register order: slots (hi, e) <-> j_local =
// [0,1,2,3,8,9,10,11][e] + 4*hi within the 16-token chunk starting at c0*8.
// Two 8B reads: chunk c0 half hi, chunk c0+1 half hi (xor-swizzled rows).
__device__ __forceinline__ bf16x8 vsplit(const short* lbase, int row, int c0, int hi) {
    const int r7 = row & 7;
    const int pc0 = c0 ^ r7, pc1 = (c0 + 1) ^ r7;
    const unsigned* b = (const unsigned*)(lbase + row * 64);
    const int o0 = pc0 * 4 + hi * 2;   // dword offset within the 32-dword row
    const int o1 = pc1 * 4 + hi * 2;
    union { unsigned u[4]; bf16x8 v; } t;
    t.u[0] = b[o0]; t.u[1] = b[o0 + 1];
    t.u[2] = b[o1]; t.u[3] = b[o1 + 1];
    return t.v;
}

// ---------------------------------------------------------------------------
// gemm128 core: C[128x128] = A[128x384] · B[128x384]^T, both k-contig rows,
// stride CCH. SINGLE-buffered phased loop (stage -> bar -> compute -> bar),
// 32 KB LDS -> 3 blocks/CU (one residency round at 576-block grids).
// Cross-block wave overlap (m114) replaces the intra-block double buffer.
// S layout: A tile at S[0..8191], B tile at S[8192..16383].
// ---------------------------------------------------------------------------
__device__ __forceinline__ void gemm128_core(
    const short* __restrict__ Ag, const short* __restrict__ Bg,
    short* S, f32x4 acc[4][4])
{
    const int tid = threadIdx.x, lane = tid & 63;
    const int l15 = tid & 15, quad = (tid >> 4) & 3, wv = tid >> 6;

#pragma unroll
    for (int kc = 0; kc < 6; ++kc) {
        stage_tile(Ag + kc * 64, CCH, S, wv, lane);
        stage_tile(Ag + kc * 64 + 64 * CCH, CCH, S + 4096, wv, lane);
        stage_tile(Bg + kc * 64, CCH, S + 8192, wv, lane);
        stage_tile(Bg + kc * 64 + 64 * CCH, CCH, S + 12288, wv, lane);
        __syncthreads();
        const short* Atile = S + (wv >> 1) * 4096;          // wi tile
        const short* Btile = S + 8192 + (wv & 1) * 4096;    // wj tile
#pragma unroll
        for (int h = 0; h < 2; ++h) {
            bf16x8 a[4], b[4];
#pragma unroll
            for (int s = 0; s < 4; ++s) {
                a[s] = frag_read(Atile, s * 16 + l15, h * 4 + quad);
                b[s] = frag_read(Btile, s * 16 + l15, h * 4 + quad);
            }
#pragma unroll
            for (int si = 0; si < 4; ++si)
#pragma unroll
                for (int sj = 0; sj < 4; ++sj)
                    acc[si][sj] = MFMA16(a[si], b[sj], acc[si][sj]);
        }
        __syncthreads();
    }
}

// Epilogue: repack the 128x128 bf16 C-tile through cbuf (= the 32 KB SMEM,
// free after the K-loop) so global stores are b128.
__device__ __forceinline__ void epilogue_bf16(
    f32x4 acc[4][4], short* cbuf,
    short* __restrict__ out, size_t obase, int ostride)
{
    const int tid = threadIdx.x;
    const int l15 = tid & 15, quad = (tid >> 4) & 3, wv = tid >> 6;
    const int wi = (wv >> 1) * 64, wj = (wv & 1) * 64;
    __syncthreads();
#pragma unroll
    for (int si = 0; si < 4; ++si)
#pragma unroll
        for (int sj = 0; sj < 4; ++sj)
#pragma unroll
            for (int rr = 0; rr < 4; ++rr)
                cbuf[(wi + si * 16 + quad * 4 + rr) * 128 + wj + sj * 16 + l15] =
                    f2b(acc[si][sj][rr]);
    __syncthreads();
#pragma unroll
    for (int pass = 0; pass < 8; ++pass) {
        const int row = pass * 16 + (tid >> 4);     // 0..127
        bf16x8 vchunk = *(const bf16x8*)(cbuf + row * 128 + l15 * 8);
        *(bf16x8*)(out + obase + (size_t)row * ostride + l15 * 8) = vchunk;
    }
}

// ---------------------------------------------------------------------------
// prep: fused transpose+convert (id<1536), weight convert (id<2112),
// amap zero (id>=2112). grid 2120.
// ---------------------------------------------------------------------------
__global__ __launch_bounds__(256) void prep(
    const float* __restrict__ Xq, const float* __restrict__ Xc,
    const float* __restrict__ w0, const float* __restrict__ w1,
    const float* __restrict__ w2, const float* __restrict__ w3,
    short* __restrict__ Xtq, short* __restrict__ Xtc,
    short* __restrict__ o0, short* __restrict__ o1,
    short* __restrict__ o2, short* __restrict__ o3,
    float* __restrict__ amap)
{
    __shared__ float tile[64][65];
    const int id = blockIdx.x, tid = threadIdx.x;
    if (id < 1536) {
        const int zz = id % 16, t = id / 16;
        const int n0 = (t % 16) * 64, c0 = (t / 16) * 64;
        const float* X = (zz < 8) ? Xq : Xc;
        short* Xt      = (zz < 8) ? Xtq : Xtc;
        const int b = zz & 7;
        const int tx = tid & 15, ty = tid >> 4;
#pragma unroll
        for (int rr = 0; rr < 4; ++rr) {
            const int c = rr * 16 + ty;
            float4 v = *(const float4*)&X[((size_t)(b * CCH + c0 + c)) * NTOK + n0 + tx * 4];
            tile[c][tx * 4 + 0] = v.x; tile[c][tx * 4 + 1] = v.y;
            tile[c][tx * 4 + 2] = v.z; tile[c][tx * 4 + 3] = v.w;
        }
        __syncthreads();
        const int n = tid >> 2, cb = (tid & 3) * 16;
        short tmp[16];
#pragma unroll
        for (int cc = 0; cc < 16; ++cc) tmp[cc] = f2b(tile[cb + cc][n]);
        short* dst = &Xt[((size_t)(b * NTOK + n0 + n)) * CCH + c0 + cb];
        *(int4*)dst = *(int4*)&tmp[0];
        *(int4*)(dst + 8) = *(int4*)&tmp[8];
    } else if (id < 2112) {
        const int w = id - 1536;
        const int which = w / 144;
        const int idx = (w % 144) * 256 + tid;
        const float* s = which == 0 ? w0 : which == 1 ? w1 : which == 2 ? w2 : w3;
        short* d       = which == 0 ? o0 : which == 1 ? o1 : which == 2 ? o2 : o3;
        float4 v = ((const float4*)s)[idx];
        short4 o = make_short4(f2b(v.x), f2b(v.y), f2b(v.z), f2b(v.w));
        ((short4*)d)[idx] = o;
    } else {
        const int o = (id - 2112) * 1024 + tid * 4;
        float4 z = {0.f, 0.f, 0.f, 0.f};
        *(float4*)&amap[o] = z;
    }
}

// ---------------------------------------------------------------------------
// Fused QKV projection, 128x128 tiles. 576 blocks: b=id%8 (XCD-local),
// r=id/8: which=r/24 (0:Q,1:K tok-major; 2:V ch-major), tt=r%24.
// Q output pre-scaled by QSCALE. 32 KB LDS -> one residency round.
// ---------------------------------------------------------------------------
__global__ __launch_bounds__(256, 3) void gemm_qkv(
    const short* __restrict__ xtq, const short* __restrict__ xtc,
    const short* __restrict__ wq, const short* __restrict__ wk,
    const short* __restrict__ wvm,
    short* __restrict__ qout, short* __restrict__ kout, short* __restrict__ vout)
{
    __shared__ __align__(16) short SMEM[16384];   // 32 KB: A | B, cbuf in epi
    const int id = blockIdx.x;
    const int b = id & 7, r = id >> 3;
    const int which = r / 24, tt = r % 24;

    const short *Ag, *Bg;
    short* out;
    size_t obase;
    int ostride;
    if (which < 2) {
        const int it = tt / 3, jt = tt % 3;
        const short* x = (which == 0) ? xtq : xtc;
        const short* W = (which == 0) ? wq : wk;
        Ag = x + ((size_t)(b * NTOK + it * 128)) * CCH;
        Bg = W + (size_t)(jt * 128) * CCH;
        out = (which == 0) ? qout : kout;
        obase = ((size_t)(b * NTOK + it * 128)) * CCH + jt * 128;
        ostride = CCH;
    } else {
        const int ct = tt % 3, nt = tt / 3;
        Ag = wvm + (size_t)(ct * 128) * CCH;
        Bg = xtc + ((size_t)(b * NTOK + nt * 128)) * CCH;
        out = vout;
        obase = ((size_t)(b * CCH + ct * 128)) * NTOK + nt * 128;
        ostride = NTOK;
    }

    f32x4 z4 = {0.f, 0.f, 0.f, 0.f};
    f32x4 acc[4][4];
#pragma unroll
    for (int si = 0; si < 4; ++si)
#pragma unroll
        for (int sj = 0; sj < 4; ++sj) acc[si][sj] = z4;

    gemm128_core(Ag, Bg, &SMEM[0], acc);

    if (which == 0) {
#pragma unroll
        for (int si = 0; si < 4; ++si)
#pragma unroll
            for (int sj = 0; sj < 4; ++sj)
#pragma unroll
                for (int rr = 0; rr < 4; ++rr)
                    acc[si][sj][rr] *= QSCALE;
    }
    epilogue_bf16(acc, &SMEM[0], out, obase, ostride);
}

// ---------------------------------------------------------------------------
// Output projection, 128x128 tiles, fp32 out + bias. 192 blocks.
// ---------------------------------------------------------------------------
__global__ __launch_bounds__(256, 3) void o_proj(
    const short* __restrict__ wo, const short* __restrict__ omid,
    const float* __restrict__ bias, float* __restrict__ Y)
{
    __shared__ __align__(16) short SMEM[16384];   // 32 KB
    const int id = blockIdx.x;
    const int b = id & 7, r = id >> 3;
    const int ct = r % 3, nt = r / 3;

    const short* Ag = wo + (size_t)(ct * 128) * CCH;
    const short* Bg = omid + ((size_t)(b * NTOK + nt * 128)) * CCH;

    f32x4 z4 = {0.f, 0.f, 0.f, 0.f};
    f32x4 acc[4][4];
#pragma unroll
    for (int si = 0; si < 4; ++si)
#pragma unroll
        for (int sj = 0; sj < 4; ++sj) acc[si][sj] = z4;

    gemm128_core(Ag, Bg, &SMEM[0], acc);

    const int tid = threadIdx.x;
    const int l15 = tid & 15, quad = (tid >> 4) & 3, wv = tid >> 6;
    const int wi = (wv >> 1) * 64, wj = (wv & 1) * 64;
#pragma unroll
    for (int si = 0; si < 4; ++si) {
#pragma unroll
        for (int rr = 0; rr < 4; ++rr) {
            const int ch = ct * 128 + wi + si * 16 + quad * 4 + rr;
            const float bv = bias[ch];
#pragma unroll
            for (int sj = 0; sj < 4; ++sj)
                Y[((size_t)(b * CCH + ch)) * NTOK + nt * 128 + wj + sj * 16 + l15] =
                    acc[si][sj][rr] + bv;
        }
    }
}

// ---------------------------------------------------------------------------
// Fused attention + amap — single pass, swapped-QK^T 32x32 MFMA, in-register
// P (vsplit operand pairing, verified r2). jsub-split schedule (verified r4):
// ALL 4 waves compute EVERY tile; wave = (isub = (wv&1)*32, js = wv>>1)
// computes its fixed jsub half; js=0 waves stage next-K, js=1 stage next-V
// BEFORE their compute. Epilogue identical to verified r2/r4.
// amap tail: verified amap_k body, but walking tiles DESCENDING 15..0 —
// tiles 15 (Kst[1]) and 14 (Kst[0]) are already resident from the main loop
// in the same swizzled format, so the tail has no cold prologue; distance-1
// prefetch stages jt-1 into Kst[cur^1] (parity works out exactly).
// ---------------------------------------------------------------------------
__global__ __launch_bounds__(256, 3) void attn(
    const short* __restrict__ qt, const short* __restrict__ kt,
    const short* __restrict__ vc, short* __restrict__ omid,
    float* __restrict__ amap)
{
    __shared__ __align__(16) short Kst[2][4096];   // 16 KB (64 tok x 64 ch)
    __shared__ __align__(16) short Vst[2][4096];   // 16 KB (64 ch x 64 tok)
    __shared__ float obuf[4][16][64];              // 16 KB epilogue combine
    __shared__ float denbuf[4][64];                // 1 KB
    __shared__ float rden_sh[2][32];
    __shared__ float colbuf[2][4][64];             // 2 KB (amap tail)

    const int tid = threadIdx.x, lane = tid & 63;
    const int l31 = lane & 31, hi = lane >> 5;
    const int wv = tid >> 6;
    const int isub = (wv & 1) * 32;
    const int js = wv >> 1;            // this wave's fixed jsub

    const int id = blockIdx.x;
    const int b = id & 7, rr_ = id >> 3;
    const int h = rr_ % 6, i0 = (rr_ / 6) * 64;

    const size_t hoff = (size_t)b * NTOK * CCH + h * DHEAD;
    const short* Kg = kt + hoff;                                   // stride CCH
    const short* Vg = vc + ((size_t)(b * CCH + h * DHEAD)) * NTOK; // stride NTOK

    // Q B-frags hoisted: lane holds Q[i = i0+isub+l31, d = m*16 + hi*8 ..+8]
    const short* qp = qt + hoff + (size_t)(i0 + isub + l31) * CCH + hi * 8;
    bf16x8 qf[4];
#pragma unroll
    for (int m = 0; m < 4; ++m) qf[m] = *(const bf16x8*)(qp + m * 16);

    // prologue: all 4 waves stage tile 0 (K and V)
    stage_tile(Kg, CCH, Kst[0], wv, lane);
    stage_tile(Vg, NTOK, Vst[0], wv, lane);
    __syncthreads();

    const f32x16 z16 = {0,0,0,0,0,0,0,0,0,0,0,0,0,0,0,0};
    f32x16 oacc0 = z16, oacc1 = z16;   // d 0..31 / 32..63
    float den = 0.f;

    for (int jt = 0; jt < 16; ++jt) {
        const int cur = jt & 1;
        // stage next tile first: js=0 waves bring K, js=1 waves bring V.
        if (jt < 15) {
            if (js == 0)
                stage_tile_2w(Kg + (size_t)(jt + 1) * 64 * CCH, CCH,
                              Kst[cur ^ 1], wv & 1, lane);
            else
                stage_tile_2w(Vg + (size_t)(jt + 1) * 64, NTOK,
                              Vst[cur ^ 1], wv & 1, lane);
        }
        // compute this wave's jsub on the current tile
        {
            const short* Kb = Kst[cur];
            const short* Vb = Vst[cur];
            f32x16 s = z16;
#pragma unroll
            for (int m = 0; m < 4; ++m)
                s = MFMA32(frag_read(Kb, js * 32 + l31, 2 * m + hi), qf[m], s);
            bf16x8 pa0, pa1;
#pragma unroll
            for (int e = 0; e < 8; ++e) {
                const float x0 = EXP2(s[e]);
                const float x1 = EXP2(s[8 + e]);
                den += x0 + x1;
                pa0[e] = (__bf16)x0;
                pa1[e] = (__bf16)x1;
            }
            oacc0 = MFMA32(pa0, vsplit(Vb, l31,      js * 4,     hi), oacc0);
            oacc0 = MFMA32(pa1, vsplit(Vb, l31,      js * 4 + 2, hi), oacc0);
            oacc1 = MFMA32(pa0, vsplit(Vb, 32 + l31, js * 4,     hi), oacc1);
            oacc1 = MFMA32(pa1, vsplit(Vb, 32 + l31, js * 4 + 2, hi), oacc1);
        }
        __syncthreads();
    }

    // ---- epilogue: cross-js combine, normalize, store (verified r2) ----
    const int dh = js;                 // this wave finalizes d-half dh
    if (dh == 0) {
#pragma unroll
        for (int g2 = 0; g2 < 16; ++g2) obuf[wv][g2][lane] = oacc1[g2];
    } else {
#pragma unroll
        for (int g2 = 0; g2 < 16; ++g2) obuf[wv][g2][lane] = oacc0[g2];
    }
    denbuf[wv][lane] = den;
    __syncthreads();

    const int g = wv & 1;
    const float dtot = denbuf[g][l31] + denbuf[g][l31 + 32]
                     + denbuf[g | 2][l31] + denbuf[g | 2][l31 + 32];
    const float rden = 1.0f / dtot;
    if (wv < 2 && lane < 32)
        rden_sh[wv][lane] = rden;
    __syncthreads();

#pragma unroll
    for (int reg = 0; reg < 16; ++reg) {
        const int crw = (reg & 3) + 8 * (reg >> 2) + 4 * hi;     // i-local 0..31
        const float rd = rden_sh[g][crw];
        const float okeep = (dh == 0) ? oacc0[reg] : oacc1[reg];
        const float ov = (okeep + obuf[wv ^ 2][reg][lane]) * rd;
        omid[((size_t)(b * NTOK + i0 + isub + crw)) * CCH + h * DHEAD + dh * 32 + l31] =
            f2b(ov);
    }

    // ---- amap tail (verified amap_k body; descending tiles, hot start) ----
    const int l15 = tid & 15, quad = (tid >> 4) & 3;
    const short* qp2 = qt + hoff + (size_t)(i0 + wv * 16 + l15) * CCH + quad * 8;
    const bf16x8 qa0 = *(const bf16x8*)qp2;
    const bf16x8 qa1 = *(const bf16x8*)(qp2 + 32);

    float rdl[4];
#pragma unroll
    for (int r = 0; r < 4; ++r) {
        const int row = wv * 16 + quad * 4 + r;                  // 0..63
        rdl[r] = rden_sh[row >> 5][row & 31];
    }
    // Kst[1] = tile 15, Kst[0] = tile 14 — still valid (nothing wrote Kst
    // since the main loop's final barrier; epilogue used obuf/denbuf only).

    for (int jt = 15; jt >= 0; --jt) {
        const int cur = jt & 1;
        if (jt <= 14 && jt >= 1)
            stage_tile(Kg + (size_t)(jt - 1) * 64 * CCH, CCH, Kst[cur ^ 1], wv, lane);
        f32x4 z4 = {0.f, 0.f, 0.f, 0.f};
        f32x4 s[4] = {z4, z4, z4, z4};
#pragma unroll
        for (int ns = 0; ns < 4; ++ns) {
            const int row = ns * 16 + l15;
            bf16x8 k0 = frag_read(Kst[cur], row, quad);
            bf16x8 k1 = frag_read(Kst[cur], row, quad + 4);
            s[ns] = MFMA16(qa0, k0, s[ns]);
            s[ns] = MFMA16(qa1, k1, s[ns]);
        }
#pragma unroll
        for (int ns = 0; ns < 4; ++ns) {
            float cs = EXP2(s[ns][0]) * rdl[0] + EXP2(s[ns][1]) * rdl[1]
                     + EXP2(s[ns][2]) * rdl[2] + EXP2(s[ns][3]) * rdl[3];
            cs += __shfl_xor(cs, 16);
            cs += __shfl_xor(cs, 32);
            if (quad == 0) colbuf[cur][wv][ns * 16 + l15] = cs;
        }
        __syncthreads();
        if (tid < 64) {
            const float t = colbuf[cur][0][tid] + colbuf[cur][1][tid]
                          + colbuf[cur][2][tid] + colbuf[cur][3][tid];
            atomicAdd(amap + (size_t)b * NTOK + jt * 64 + tid,
                      t * (1.0f / (HEADS * NTOK)));
        }
    }
}

// ---------------------------------------------------------------------------
extern "C" void kernel_launch(void* const* d_in, const int* in_sizes, int n_in,
                              void* d_out, int out_size, void* d_ws, size_t ws_size,
                              hipStream_t stream)
{
    const float* query   = (const float*)d_in[0];
    const float* context = (const float*)d_in[1];
    const float* Wq      = (const float*)d_in[2];
    const float* Wk      = (const float*)d_in[3];
    const float* Wv      = (const float*)d_in[4];
    const float* Wo      = (const float*)d_in[5];
    const float* bo      = (const float*)d_in[6];

    float* out = (float*)d_out;                          // [8,384,1024] fp32
    const size_t out_elems = (size_t)BATCH * CCH * NTOK;
    float* attn_map = out + out_elems;                   // [8,1024] fp32

    short* ws = (short*)d_ws;
    const size_t XT = (size_t)BATCH * NTOK * CCH;
    const size_t WSZ = (size_t)CCH * CCH;
    short* xtq  = ws;
    short* xtc  = xtq + XT;
    short* wqb  = xtc + XT;
    short* wkb  = wqb + WSZ;
    short* wvb  = wkb + WSZ;
    short* wob  = wvb + WSZ;
    short* qtb  = wob + WSZ;
    short* ktb  = qtb + XT;
    short* vcb  = ktb + XT;
    short* omid = vcb + XT;

    const dim3 blk(256);

    prep<<<dim3(2120), blk, 0, stream>>>(query, context, Wq, Wk, Wv, Wo,
                                         xtq, xtc, wqb, wkb, wvb, wob, attn_map);

    gemm_qkv<<<dim3(576), blk, 0, stream>>>(xtq, xtc, wqb, wkb, wvb,
                                            qtb, ktb, vcb);

    attn<<<dim3(768), blk, 0, stream>>>(qtb, ktb, vcb, omid, attn_map);

    o_proj<<<dim3(192), blk, 0, stream>>>(wob, omid, bo, out);
}

// Round 6
// 143.165 us; speedup vs baseline: 1.1800x; 1.0189x over previous
//
#include <hip/hip_runtime.h>

// Problem constants
#define BATCH 8
#define CCH   384      // channels C == INNER
#define NTOK  1024     // H*W
#define HEADS 6
#define DHEAD 64
// softmax scale 1/8 and log2(e) folded into Q at projection time:
// qout = Q * 0.125 * 1.4426950408889634, attn uses exp2(s) = bare v_exp.
#define QSCALE 0.18033688011112042f

typedef __bf16 bf16x8 __attribute__((ext_vector_type(8)));
typedef float  f32x4  __attribute__((ext_vector_type(4)));
typedef float  f32x16 __attribute__((ext_vector_type(16)));

#define MFMA16(a, b, c) __builtin_amdgcn_mfma_f32_16x16x32_bf16((a), (b), (c), 0, 0, 0)
#define MFMA32(a, b, c) __builtin_amdgcn_mfma_f32_32x32x16_bf16((a), (b), (c), 0, 0, 0)
#define EXP2(x) __builtin_amdgcn_exp2f(x)

// fp32 -> bf16 RNE, raw bits
__device__ __forceinline__ short f2b(float x) {
    unsigned u = __float_as_uint(x);
    u += 0x7fffu + ((u >> 16) & 1u);
    return (short)(u >> 16);
}

// async global->LDS, 16B/lane. LDS dst = wave-uniform base + lane*16.
__device__ __forceinline__ void gld_lds16(const short* gp, short* lp) {
    __builtin_amdgcn_global_load_lds(
        (const __attribute__((address_space(1))) void*)gp,
        (__attribute__((address_space(3))) void*)lp, 16, 0, 0);
}

// ---- 64x64 xor-swizzled tile staging (4 waves) — verified r3/r4 ----
__device__ __forceinline__ void stage_tile(const short* gbase, size_t gstride,
                                           short* lbase, int wv, int lane) {
#pragma unroll
    for (int t = 0; t < 2; ++t) {
        const int row = t * 8 + (lane >> 3);
        const int c   = (lane & 7) ^ (row & 7);
        gld_lds16(gbase + (size_t)(wv * 16 + row) * gstride + c * 8,
                  lbase + (wv * 16 + t * 8) * 64);
    }
}
// same tile, staged by 2 waves (sw = 0/1), 4 gld per thread
__device__ __forceinline__ void stage_tile_2w(const short* gbase, size_t gstride,
                                              short* lbase, int sw, int lane) {
#pragma unroll
    for (int t = 0; t < 4; ++t) {
        const int row = sw * 32 + t * 8 + (lane >> 3);
        const int c   = (lane & 7) ^ (row & 7);
        gld_lds16(gbase + (size_t)row * gstride + c * 8,
                  lbase + (sw * 32 + t * 8) * 64);
    }
}
__device__ __forceinline__ bf16x8 frag_read(const short* lbase, int row, int c) {
    const int pc = c ^ (row & 7);
    return *(const bf16x8*)(lbase + row * 64 + pc * 8);
}

// Split V fragment read: element e of result holds V[row][tok], tok matching
// the NATURAL post-QK P register order: slots (hi, e) <-> j_local =
// [0,1,2,3,8,9,10,11][e] + 4*hi within the 16-token chunk starting at c0*8.
// Two 8B reads: chunk c0 half hi, chunk c0+1 half hi (xor-swizzled rows).
__device__ __forceinline__ bf16x8 vsplit(const short* lbase, int row, int c0, int hi) {
    const int r7 = row & 7;
    const int pc0 = c0 ^ r7, pc1 = (c0 + 1) ^ r7;
    const unsigned* b = (const unsigned*)(lbase + row * 64);
    const int o0 = pc0 * 4 + hi * 2;   // dword offset within the 32-dword row
    const int o1 = pc1 * 4 + hi * 2;
    union { unsigned u[4]; bf16x8 v; } t;
    t.u[0] = b[o0]; t.u[1] = b[o0 + 1];
    t.u[2] = b[o1]; t.u[3] = b[o1 + 1];
    return t.v;
}

// ---------------------------------------------------------------------------
// gemm128 core: C[128x128] = A[128x384] · B[128x384]^T, both k-contig rows,
// stride CCH. SINGLE-buffered phased loop (stage -> bar -> compute -> bar),
// 32 KB LDS -> 3 blocks/CU (one residency round at 576-block grids).
// Cross-block wave overlap (m114) replaces the intra-block double buffer.
// S layout: A tile at S[0..8191], B tile at S[8192..16383].
// ---------------------------------------------------------------------------
__device__ __forceinline__ void gemm128_core(
    const short* __restrict__ Ag, const short* __restrict__ Bg,
    short* S, f32x4 acc[4][4])
{
    const int tid = threadIdx.x, lane = tid & 63;
    const int l15 = tid & 15, quad = (tid >> 4) & 3, wv = tid >> 6;

#pragma unroll
    for (int kc = 0; kc < 6; ++kc) {
        stage_tile(Ag + kc * 64, CCH, S, wv, lane);
        stage_tile(Ag + kc * 64 + 64 * CCH, CCH, S + 4096, wv, lane);
        stage_tile(Bg + kc * 64, CCH, S + 8192, wv, lane);
        stage_tile(Bg + kc * 64 + 64 * CCH, CCH, S + 12288, wv, lane);
        __syncthreads();
        const short* Atile = S + (wv >> 1) * 4096;          // wi tile
        const short* Btile = S + 8192 + (wv & 1) * 4096;    // wj tile
#pragma unroll
        for (int h = 0; h < 2; ++h) {
            bf16x8 a[4], b[4];
#pragma unroll
            for (int s = 0; s < 4; ++s) {
                a[s] = frag_read(Atile, s * 16 + l15, h * 4 + quad);
                b[s] = frag_read(Btile, s * 16 + l15, h * 4 + quad);
            }
#pragma unroll
            for (int si = 0; si < 4; ++si)
#pragma unroll
                for (int sj = 0; sj < 4; ++sj)
                    acc[si][sj] = MFMA16(a[si], b[sj], acc[si][sj]);
        }
        __syncthreads();
    }
}

// Epilogue: repack the 128x128 bf16 C-tile through cbuf (= the 32 KB SMEM,
// free after the K-loop) so global stores are b128.
__device__ __forceinline__ void epilogue_bf16(
    f32x4 acc[4][4], short* cbuf,
    short* __restrict__ out, size_t obase, int ostride)
{
    const int tid = threadIdx.x;
    const int l15 = tid & 15, quad = (tid >> 4) & 3, wv = tid >> 6;
    const int wi = (wv >> 1) * 64, wj = (wv & 1) * 64;
    __syncthreads();
#pragma unroll
    for (int si = 0; si < 4; ++si)
#pragma unroll
        for (int sj = 0; sj < 4; ++sj)
#pragma unroll
            for (int rr = 0; rr < 4; ++rr)
                cbuf[(wi + si * 16 + quad * 4 + rr) * 128 + wj + sj * 16 + l15] =
                    f2b(acc[si][sj][rr]);
    __syncthreads();
#pragma unroll
    for (int pass = 0; pass < 8; ++pass) {
        const int row = pass * 16 + (tid >> 4);     // 0..127
        bf16x8 vchunk = *(const bf16x8*)(cbuf + row * 128 + l15 * 8);
        *(bf16x8*)(out + obase + (size_t)row * ostride + l15 * 8) = vchunk;
    }
}

// ---------------------------------------------------------------------------
// prep: fused transpose+convert (id<1536), weight convert (id<2112),
// amap zero (id>=2112). grid 2120.
// ---------------------------------------------------------------------------
__global__ __launch_bounds__(256) void prep(
    const float* __restrict__ Xq, const float* __restrict__ Xc,
    const float* __restrict__ w0, const float* __restrict__ w1,
    const float* __restrict__ w2, const float* __restrict__ w3,
    short* __restrict__ Xtq, short* __restrict__ Xtc,
    short* __restrict__ o0, short* __restrict__ o1,
    short* __restrict__ o2, short* __restrict__ o3,
    float* __restrict__ amap)
{
    __shared__ float tile[64][65];
    const int id = blockIdx.x, tid = threadIdx.x;
    if (id < 1536) {
        const int zz = id % 16, t = id / 16;
        const int n0 = (t % 16) * 64, c0 = (t / 16) * 64;
        const float* X = (zz < 8) ? Xq : Xc;
        short* Xt      = (zz < 8) ? Xtq : Xtc;
        const int b = zz & 7;
        const int tx = tid & 15, ty = tid >> 4;
#pragma unroll
        for (int rr = 0; rr < 4; ++rr) {
            const int c = rr * 16 + ty;
            float4 v = *(const float4*)&X[((size_t)(b * CCH + c0 + c)) * NTOK + n0 + tx * 4];
            tile[c][tx * 4 + 0] = v.x; tile[c][tx * 4 + 1] = v.y;
            tile[c][tx * 4 + 2] = v.z; tile[c][tx * 4 + 3] = v.w;
        }
        __syncthreads();
        const int n = tid >> 2, cb = (tid & 3) * 16;
        short tmp[16];
#pragma unroll
        for (int cc = 0; cc < 16; ++cc) tmp[cc] = f2b(tile[cb + cc][n]);
        short* dst = &Xt[((size_t)(b * NTOK + n0 + n)) * CCH + c0 + cb];
        *(int4*)dst = *(int4*)&tmp[0];
        *(int4*)(dst + 8) = *(int4*)&tmp[8];
    } else if (id < 2112) {
        const int w = id - 1536;
        const int which = w / 144;
        const int idx = (w % 144) * 256 + tid;
        const float* s = which == 0 ? w0 : which == 1 ? w1 : which == 2 ? w2 : w3;
        short* d       = which == 0 ? o0 : which == 1 ? o1 : which == 2 ? o2 : o3;
        float4 v = ((const float4*)s)[idx];
        short4 o = make_short4(f2b(v.x), f2b(v.y), f2b(v.z), f2b(v.w));
        ((short4*)d)[idx] = o;
    } else {
        const int o = (id - 2112) * 1024 + tid * 4;
        float4 z = {0.f, 0.f, 0.f, 0.f};
        *(float4*)&amap[o] = z;
    }
}

// ---------------------------------------------------------------------------
// Fused QKV projection, 128x128 tiles. 576 blocks: b=id%8 (XCD-local),
// r=id/8: which=r/24 (0:Q,1:K tok-major; 2:V ch-major), tt=r%24.
// Q output pre-scaled by QSCALE. 32 KB LDS -> one residency round.
// ---------------------------------------------------------------------------
__global__ __launch_bounds__(256, 3) void gemm_qkv(
    const short* __restrict__ xtq, const short* __restrict__ xtc,
    const short* __restrict__ wq, const short* __restrict__ wk,
    const short* __restrict__ wvm,
    short* __restrict__ qout, short* __restrict__ kout, short* __restrict__ vout)
{
    __shared__ __align__(16) short SMEM[16384];   // 32 KB: A | B, cbuf in epi
    const int id = blockIdx.x;
    const int b = id & 7, r = id >> 3;
    const int which = r / 24, tt = r % 24;

    const short *Ag, *Bg;
    short* out;
    size_t obase;
    int ostride;
    if (which < 2) {
        const int it = tt / 3, jt = tt % 3;
        const short* x = (which == 0) ? xtq : xtc;
        const short* W = (which == 0) ? wq : wk;
        Ag = x + ((size_t)(b * NTOK + it * 128)) * CCH;
        Bg = W + (size_t)(jt * 128) * CCH;
        out = (which == 0) ? qout : kout;
        obase = ((size_t)(b * NTOK + it * 128)) * CCH + jt * 128;
        ostride = CCH;
    } else {
        const int ct = tt % 3, nt = tt / 3;
        Ag = wvm + (size_t)(ct * 128) * CCH;
        Bg = xtc + ((size_t)(b * NTOK + nt * 128)) * CCH;
        out = vout;
        obase = ((size_t)(b * CCH + ct * 128)) * NTOK + nt * 128;
        ostride = NTOK;
    }

    f32x4 z4 = {0.f, 0.f, 0.f, 0.f};
    f32x4 acc[4][4];
#pragma unroll
    for (int si = 0; si < 4; ++si)
#pragma unroll
        for (int sj = 0; sj < 4; ++sj) acc[si][sj] = z4;

    gemm128_core(Ag, Bg, &SMEM[0], acc);

    if (which == 0) {
#pragma unroll
        for (int si = 0; si < 4; ++si)
#pragma unroll
            for (int sj = 0; sj < 4; ++sj)
#pragma unroll
                for (int rr = 0; rr < 4; ++rr)
                    acc[si][sj][rr] *= QSCALE;
    }
    epilogue_bf16(acc, &SMEM[0], out, obase, ostride);
}

// ---------------------------------------------------------------------------
// Output projection, 128x128 tiles, fp32 out + bias. 192 blocks.
// ---------------------------------------------------------------------------
__global__ __launch_bounds__(256, 3) void o_proj(
    const short* __restrict__ wo, const short* __restrict__ omid,
    const float* __restrict__ bias, float* __restrict__ Y)
{
    __shared__ __align__(16) short SMEM[16384];   // 32 KB
    const int id = blockIdx.x;
    const int b = id & 7, r = id >> 3;
    const int ct = r % 3, nt = r / 3;

    const short* Ag = wo + (size_t)(ct * 128) * CCH;
    const short* Bg = omid + ((size_t)(b * NTOK + nt * 128)) * CCH;

    f32x4 z4 = {0.f, 0.f, 0.f, 0.f};
    f32x4 acc[4][4];
#pragma unroll
    for (int si = 0; si < 4; ++si)
#pragma unroll
        for (int sj = 0; sj < 4; ++sj) acc[si][sj] = z4;

    gemm128_core(Ag, Bg, &SMEM[0], acc);

    const int tid = threadIdx.x;
    const int l15 = tid & 15, quad = (tid >> 4) & 3, wv = tid >> 6;
    const int wi = (wv >> 1) * 64, wj = (wv & 1) * 64;
#pragma unroll
    for (int si = 0; si < 4; ++si) {
#pragma unroll
        for (int rr = 0; rr < 4; ++rr) {
            const int ch = ct * 128 + wi + si * 16 + quad * 4 + rr;
            const float bv = bias[ch];
#pragma unroll
            for (int sj = 0; sj < 4; ++sj)
                Y[((size_t)(b * CCH + ch)) * NTOK + nt * 128 + wj + sj * 16 + l15] =
                    acc[si][sj][rr] + bv;
        }
    }
}

// ---------------------------------------------------------------------------
// Attention O-pass — single pass, swapped-QK^T 32x32 MFMA, in-register P
// (vsplit operand pairing, verified r2), jsub-split schedule (verified r4).
// amap moved to its own j-split kernel; this kernel writes omid + rws (rden).
// LDS shrunk to ~33 KB: the epilogue obuf is ALIASED onto Vst (exact 16 KB
// fit) — safe because the last Vst read (jt=15) precedes the loop-final
// barrier, and obuf is only touched after it.
// ---------------------------------------------------------------------------
__global__ __launch_bounds__(256, 3) void attn(
    const short* __restrict__ qt, const short* __restrict__ kt,
    const short* __restrict__ vc, short* __restrict__ omid,
    float* __restrict__ rws)
{
    __shared__ __align__(16) short Kst[2][4096];   // 16 KB (64 tok x 64 ch)
    __shared__ __align__(16) short Vst[2][4096];   // 16 KB; obuf alias in epi
    __shared__ float denbuf[4][64];                // 1 KB
    __shared__ float rden_sh[2][32];
    float (*obuf)[16][64] = (float (*)[16][64])(&Vst[0][0]);  // 4*16*64 f32 = 16 KB

    const int tid = threadIdx.x, lane = tid & 63;
    const int l31 = lane & 31, hi = lane >> 5;
    const int wv = tid >> 6;
    const int isub = (wv & 1) * 32;
    const int js = wv >> 1;            // this wave's fixed jsub

    const int id = blockIdx.x;
    const int b = id & 7, rr_ = id >> 3;
    const int h = rr_ % 6, i0 = (rr_ / 6) * 64;

    const size_t hoff = (size_t)b * NTOK * CCH + h * DHEAD;
    const short* Kg = kt + hoff;                                   // stride CCH
    const short* Vg = vc + ((size_t)(b * CCH + h * DHEAD)) * NTOK; // stride NTOK

    // Q B-frags hoisted: lane holds Q[i = i0+isub+l31, d = m*16 + hi*8 ..+8]
    const short* qp = qt + hoff + (size_t)(i0 + isub + l31) * CCH + hi * 8;
    bf16x8 qf[4];
#pragma unroll
    for (int m = 0; m < 4; ++m) qf[m] = *(const bf16x8*)(qp + m * 16);

    // prologue: all 4 waves stage tile 0 (K and V)
    stage_tile(Kg, CCH, Kst[0], wv, lane);
    stage_tile(Vg, NTOK, Vst[0], wv, lane);
    __syncthreads();

    const f32x16 z16 = {0,0,0,0,0,0,0,0,0,0,0,0,0,0,0,0};
    f32x16 oacc0 = z16, oacc1 = z16;   // d 0..31 / 32..63
    float den = 0.f;

    for (int jt = 0; jt < 16; ++jt) {
        const int cur = jt & 1;
        // stage next tile first: js=0 waves bring K, js=1 waves bring V.
        if (jt < 15) {
            if (js == 0)
                stage_tile_2w(Kg + (size_t)(jt + 1) * 64 * CCH, CCH,
                              Kst[cur ^ 1], wv & 1, lane);
            else
                stage_tile_2w(Vg + (size_t)(jt + 1) * 64, NTOK,
                              Vst[cur ^ 1], wv & 1, lane);
        }
        // compute this wave's jsub on the current tile
        {
            const short* Kb = Kst[cur];
            const short* Vb = Vst[cur];
            f32x16 s = z16;
#pragma unroll
            for (int m = 0; m < 4; ++m)
                s = MFMA32(frag_read(Kb, js * 32 + l31, 2 * m + hi), qf[m], s);
            bf16x8 pa0, pa1;
#pragma unroll
            for (int e = 0; e < 8; ++e) {
                const float x0 = EXP2(s[e]);
                const float x1 = EXP2(s[8 + e]);
                den += x0 + x1;
                pa0[e] = (__bf16)x0;
                pa1[e] = (__bf16)x1;
            }
            oacc0 = MFMA32(pa0, vsplit(Vb, l31,      js * 4,     hi), oacc0);
            oacc0 = MFMA32(pa1, vsplit(Vb, l31,      js * 4 + 2, hi), oacc0);
            oacc1 = MFMA32(pa0, vsplit(Vb, 32 + l31, js * 4,     hi), oacc1);
            oacc1 = MFMA32(pa1, vsplit(Vb, 32 + l31, js * 4 + 2, hi), oacc1);
        }
        __syncthreads();
    }

    // ---- epilogue: cross-js combine, normalize, store (verified r2) ----
    // obuf lives in Vst's bytes from here on (all Vst reads are behind the
    // final loop barrier above).
    const int dh = js;                 // this wave finalizes d-half dh
    if (dh == 0) {
#pragma unroll
        for (int g2 = 0; g2 < 16; ++g2) obuf[wv][g2][lane] = oacc1[g2];
    } else {
#pragma unroll
        for (int g2 = 0; g2 < 16; ++g2) obuf[wv][g2][lane] = oacc0[g2];
    }
    denbuf[wv][lane] = den;
    __syncthreads();

    const int g = wv & 1;
    const float dtot = denbuf[g][l31] + denbuf[g][l31 + 32]
                     + denbuf[g | 2][l31] + denbuf[g | 2][l31 + 32];
    const float rden = 1.0f / dtot;
    if (wv < 2 && lane < 32) {
        rden_sh[wv][lane] = rden;
        rws[((b * 6 + h) << 10) + i0 + isub + lane] = rden;
    }
    __syncthreads();

#pragma unroll
    for (int reg = 0; reg < 16; ++reg) {
        const int crw = (reg & 3) + 8 * (reg >> 2) + 4 * hi;     // i-local 0..31
        const float rd = rden_sh[g][crw];
        const float okeep = (dh == 0) ? oacc0[reg] : oacc1[reg];
        const float ov = (okeep + obuf[wv ^ 2][reg][lane]) * rd;
        omid[((size_t)(b * NTOK + i0 + isub + crw)) * CCH + h * DHEAD + dh * 32 + l31] =
            f2b(ov);
    }
}

// ---------------------------------------------------------------------------
// amap kernel, j-split: S = QK^T (non-swapped 16x16 layout: i in reg dims ->
// colsum is 3 adds + 2 shuffles), p = exp2(s)*rden[i], column-sum, atomic
// into amap. Grid 1536 = b(8) x h(6) x i-tile(16) x j-half(2); each block
// covers 8 of the 16 K-tiles. 18 KB LDS -> up to 8 blocks/CU: doubles
// block-level overlap vs the fused-tail version (6 resident at grid 1536).
// Body is the r2-verified amap_k with a jt0 offset.
// ---------------------------------------------------------------------------
__global__ __launch_bounds__(256) void amap_k(
    const short* __restrict__ qt, const short* __restrict__ kt,
    const float* __restrict__ rws, float* __restrict__ amap)
{
    __shared__ __align__(16) short Kst[2][4096];
    __shared__ float colbuf[2][4][64];

    const int tid = threadIdx.x, lane = tid & 63;
    const int l15 = tid & 15, quad = (tid >> 4) & 3, wv = tid >> 6;
    const int id = blockIdx.x;
    const int b = id & 7, r = id >> 3;          // r in 0..191
    const int h = r % 6, q = r / 6;             // q in 0..31
    const int i0 = (q >> 1) * 64;
    const int jt0 = (q & 1) * 8;

    const size_t hoff = (size_t)b * NTOK * CCH + h * DHEAD;
    const short* Kg = kt + hoff;
    const short* qp = qt + hoff + (size_t)(i0 + wv * 16 + l15) * CCH + quad * 8;
    const bf16x8 qa0 = *(const bf16x8*)qp;
    const bf16x8 qa1 = *(const bf16x8*)(qp + 32);

    float rdl[4];
#pragma unroll
    for (int rr = 0; rr < 4; ++rr)
        rdl[rr] = rws[((b * 6 + h) << 10) + i0 + wv * 16 + quad * 4 + rr];

    stage_tile(Kg + (size_t)jt0 * 64 * CCH, CCH, Kst[0], wv, lane);
    __syncthreads();

    for (int t = 0; t < 8; ++t) {
        const int jt = jt0 + t;
        const int cur = t & 1;
        if (t < 7)
            stage_tile(Kg + (size_t)(jt + 1) * 64 * CCH, CCH, Kst[cur ^ 1], wv, lane);
        f32x4 z4 = {0.f, 0.f, 0.f, 0.f};
        f32x4 s[4] = {z4, z4, z4, z4};
#pragma unroll
        for (int ns = 0; ns < 4; ++ns) {
            const int row = ns * 16 + l15;
            bf16x8 k0 = frag_read(Kst[cur], row, quad);
            bf16x8 k1 = frag_read(Kst[cur], row, quad + 4);
            s[ns] = MFMA16(qa0, k0, s[ns]);
            s[ns] = MFMA16(qa1, k1, s[ns]);
        }
#pragma unroll
        for (int ns = 0; ns < 4; ++ns) {
            float cs = EXP2(s[ns][0]) * rdl[0] + EXP2(s[ns][1]) * rdl[1]
                     + EXP2(s[ns][2]) * rdl[2] + EXP2(s[ns][3]) * rdl[3];
            cs += __shfl_xor(cs, 16);
            cs += __shfl_xor(cs, 32);
            if (quad == 0) colbuf[cur][wv][ns * 16 + l15] = cs;
        }
        __syncthreads();
        if (tid < 64) {
            const float tsum = colbuf[cur][0][tid] + colbuf[cur][1][tid]
                             + colbuf[cur][2][tid] + colbuf[cur][3][tid];
            atomicAdd(amap + (size_t)b * NTOK + jt * 64 + tid,
                      tsum * (1.0f / (HEADS * NTOK)));
        }
    }
}

// ---------------------------------------------------------------------------
extern "C" void kernel_launch(void* const* d_in, const int* in_sizes, int n_in,
                              void* d_out, int out_size, void* d_ws, size_t ws_size,
                              hipStream_t stream)
{
    const float* query   = (const float*)d_in[0];
    const float* context = (const float*)d_in[1];
    const float* Wq      = (const float*)d_in[2];
    const float* Wk      = (const float*)d_in[3];
    const float* Wv      = (const float*)d_in[4];
    const float* Wo      = (const float*)d_in[5];
    const float* bo      = (const float*)d_in[6];

    float* out = (float*)d_out;                          // [8,384,1024] fp32
    const size_t out_elems = (size_t)BATCH * CCH * NTOK;
    float* attn_map = out + out_elems;                   // [8,1024] fp32

    short* ws = (short*)d_ws;
    const size_t XT = (size_t)BATCH * NTOK * CCH;
    const size_t WSZ = (size_t)CCH * CCH;
    short* xtq  = ws;
    short* xtc  = xtq + XT;
    short* wqb  = xtc + XT;
    short* wkb  = wqb + WSZ;
    short* wvb  = wkb + WSZ;
    short* wob  = wvb + WSZ;
    short* qtb  = wob + WSZ;
    short* ktb  = qtb + XT;
    short* vcb  = ktb + XT;
    short* omid = vcb + XT;
    float* rws  = (float*)(omid + XT);                   // [8*6*1024] fp32 rden

    const dim3 blk(256);

    prep<<<dim3(2120), blk, 0, stream>>>(query, context, Wq, Wk, Wv, Wo,
                                         xtq, xtc, wqb, wkb, wvb, wob, attn_map);

    gemm_qkv<<<dim3(576), blk, 0, stream>>>(xtq, xtc, wqb, wkb, wvb,
                                            qtb, ktb, vcb);

    attn<<<dim3(768), blk, 0, stream>>>(qtb, ktb, vcb, omid, rws);

    amap_k<<<dim3(1536), blk, 0, stream>>>(qtb, ktb, rws, attn_map);

    o_proj<<<dim3(192), blk, 0, stream>>>(wob, omid, bo, out);
}

// Round 7
// 141.427 us; speedup vs baseline: 1.1945x; 1.0123x over previous
//
#include <hip/hip_runtime.h>

// Problem constants
#define BATCH 8
#define CCH   384      // channels C == INNER
#define NTOK  1024     // H*W
#define HEADS 6
#define DHEAD 64
// softmax scale 1/8 and log2(e) folded into Q at projection time:
// qout = Q * 0.125 * 1.4426950408889634, attn uses exp2(s) = bare v_exp.
#define QSCALE 0.18033688011112042f

typedef __bf16 bf16x8 __attribute__((ext_vector_type(8)));
typedef float  f32x4  __attribute__((ext_vector_type(4)));
typedef float  f32x16 __attribute__((ext_vector_type(16)));

#define MFMA16(a, b, c) __builtin_amdgcn_mfma_f32_16x16x32_bf16((a), (b), (c), 0, 0, 0)
#define MFMA32(a, b, c) __builtin_amdgcn_mfma_f32_32x32x16_bf16((a), (b), (c), 0, 0, 0)
#define EXP2(x) __builtin_amdgcn_exp2f(x)

// fp32 -> bf16 RNE, raw bits
__device__ __forceinline__ short f2b(float x) {
    unsigned u = __float_as_uint(x);
    u += 0x7fffu + ((u >> 16) & 1u);
    return (short)(u >> 16);
}

// async global->LDS, 16B/lane. LDS dst = wave-uniform base + lane*16.
__device__ __forceinline__ void gld_lds16(const short* gp, short* lp) {
    __builtin_amdgcn_global_load_lds(
        (const __attribute__((address_space(1))) void*)gp,
        (__attribute__((address_space(3))) void*)lp, 16, 0, 0);
}

// ---- 64x64 xor-swizzled tile staging (4 waves) — verified r3/r4 ----
__device__ __forceinline__ void stage_tile(const short* gbase, size_t gstride,
                                           short* lbase, int wv, int lane) {
#pragma unroll
    for (int t = 0; t < 2; ++t) {
        const int row = t * 8 + (lane >> 3);
        const int c   = (lane & 7) ^ (row & 7);
        gld_lds16(gbase + (size_t)(wv * 16 + row) * gstride + c * 8,
                  lbase + (wv * 16 + t * 8) * 64);
    }
}
// same tile, staged by 2 waves (sw = 0/1), 4 gld per thread
__device__ __forceinline__ void stage_tile_2w(const short* gbase, size_t gstride,
                                              short* lbase, int sw, int lane) {
#pragma unroll
    for (int t = 0; t < 4; ++t) {
        const int row = sw * 32 + t * 8 + (lane >> 3);
        const int c   = (lane & 7) ^ (row & 7);
        gld_lds16(gbase + (size_t)row * gstride + c * 8,
                  lbase + (sw * 32 + t * 8) * 64);
    }
}
__device__ __forceinline__ bf16x8 frag_read(const short* lbase, int row, int c) {
    const int pc = c ^ (row & 7);
    return *(const bf16x8*)(lbase + row * 64 + pc * 8);
}

// Split V fragment read: element e of result holds V[row][tok], tok matching
// the NATURAL post-QK P register order: slots (hi, e) <-> j_local =
// [0,1,2,3,8,9,10,11][e] + 4*hi within the 16-token chunk starting at c0*8.
// Two 8B reads: chunk c0 half hi, chunk c0+1 half hi (xor-swizzled rows).
__device__ __forceinline__ bf16x8 vsplit(const short* lbase, int row, int c0, int hi) {
    const int r7 = row & 7;
    const int pc0 = c0 ^ r7, pc1 = (c0 + 1) ^ r7;
    const unsigned* b = (const unsigned*)(lbase + row * 64);
    const int o0 = pc0 * 4 + hi * 2;   // dword offset within the 32-dword row
    const int o1 = pc1 * 4 + hi * 2;
    union { unsigned u[4]; bf16x8 v; } t;
    t.u[0] = b[o0]; t.u[1] = b[o0 + 1];
    t.u[2] = b[o1]; t.u[3] = b[o1 + 1];
    return t.v;
}

// ---------------------------------------------------------------------------
// gemm128 core: C[128x128] = A[128x384] · B[128x384]^T, both k-contig rows,
// stride CCH. SINGLE-buffered phased loop (stage -> bar -> compute -> bar),
// 32 KB LDS -> 3 blocks/CU. Cross-block wave overlap (m114) replaces the
// intra-block double buffer. S layout: A at S[0..8191], B at S[8192..16383].
// ---------------------------------------------------------------------------
__device__ __forceinline__ void gemm128_core(
    const short* __restrict__ Ag, const short* __restrict__ Bg,
    short* S, f32x4 acc[4][4])
{
    const int tid = threadIdx.x, lane = tid & 63;
    const int l15 = tid & 15, quad = (tid >> 4) & 3, wv = tid >> 6;

#pragma unroll
    for (int kc = 0; kc < 6; ++kc) {
        stage_tile(Ag + kc * 64, CCH, S, wv, lane);
        stage_tile(Ag + kc * 64 + 64 * CCH, CCH, S + 4096, wv, lane);
        stage_tile(Bg + kc * 64, CCH, S + 8192, wv, lane);
        stage_tile(Bg + kc * 64 + 64 * CCH, CCH, S + 12288, wv, lane);
        __syncthreads();
        const short* Atile = S + (wv >> 1) * 4096;          // wi tile
        const short* Btile = S + 8192 + (wv & 1) * 4096;    // wj tile
#pragma unroll
        for (int h = 0; h < 2; ++h) {
            bf16x8 a[4], b[4];
#pragma unroll
            for (int s = 0; s < 4; ++s) {
                a[s] = frag_read(Atile, s * 16 + l15, h * 4 + quad);
                b[s] = frag_read(Btile, s * 16 + l15, h * 4 + quad);
            }
#pragma unroll
            for (int si = 0; si < 4; ++si)
#pragma unroll
                for (int sj = 0; sj < 4; ++sj)
                    acc[si][sj] = MFMA16(a[si], b[sj], acc[si][sj]);
        }
        __syncthreads();
    }
}

// Epilogue: repack the 128x128 bf16 C-tile through cbuf (= the 32 KB SMEM,
// free after the K-loop) so global stores are b128.
__device__ __forceinline__ void epilogue_bf16(
    f32x4 acc[4][4], short* cbuf,
    short* __restrict__ out, size_t obase, int ostride)
{
    const int tid = threadIdx.x;
    const int l15 = tid & 15, quad = (tid >> 4) & 3, wv = tid >> 6;
    const int wi = (wv >> 1) * 64, wj = (wv & 1) * 64;
    __syncthreads();
#pragma unroll
    for (int si = 0; si < 4; ++si)
#pragma unroll
        for (int sj = 0; sj < 4; ++sj)
#pragma unroll
            for (int rr = 0; rr < 4; ++rr)
                cbuf[(wi + si * 16 + quad * 4 + rr) * 128 + wj + sj * 16 + l15] =
                    f2b(acc[si][sj][rr]);
    __syncthreads();
#pragma unroll
    for (int pass = 0; pass < 8; ++pass) {
        const int row = pass * 16 + (tid >> 4);     // 0..127
        bf16x8 vchunk = *(const bf16x8*)(cbuf + row * 128 + l15 * 8);
        *(bf16x8*)(out + obase + (size_t)row * ostride + l15 * 8) = vchunk;
    }
}

// ---------------------------------------------------------------------------
// prep: fused transpose+convert (id<1536), weight convert (id<2112),
// amap zero (id>=2112). grid 2120.
// ---------------------------------------------------------------------------
__global__ __launch_bounds__(256) void prep(
    const float* __restrict__ Xq, const float* __restrict__ Xc,
    const float* __restrict__ w0, const float* __restrict__ w1,
    const float* __restrict__ w2, const float* __restrict__ w3,
    short* __restrict__ Xtq, short* __restrict__ Xtc,
    short* __restrict__ o0, short* __restrict__ o1,
    short* __restrict__ o2, short* __restrict__ o3,
    float* __restrict__ amap)
{
    __shared__ float tile[64][65];
    const int id = blockIdx.x, tid = threadIdx.x;
    if (id < 1536) {
        const int zz = id % 16, t = id / 16;
        const int n0 = (t % 16) * 64, c0 = (t / 16) * 64;
        const float* X = (zz < 8) ? Xq : Xc;
        short* Xt      = (zz < 8) ? Xtq : Xtc;
        const int b = zz & 7;
        const int tx = tid & 15, ty = tid >> 4;
#pragma unroll
        for (int rr = 0; rr < 4; ++rr) {
            const int c = rr * 16 + ty;
            float4 v = *(const float4*)&X[((size_t)(b * CCH + c0 + c)) * NTOK + n0 + tx * 4];
            tile[c][tx * 4 + 0] = v.x; tile[c][tx * 4 + 1] = v.y;
            tile[c][tx * 4 + 2] = v.z; tile[c][tx * 4 + 3] = v.w;
        }
        __syncthreads();
        const int n = tid >> 2, cb = (tid & 3) * 16;
        short tmp[16];
#pragma unroll
        for (int cc = 0; cc < 16; ++cc) tmp[cc] = f2b(tile[cb + cc][n]);
        short* dst = &Xt[((size_t)(b * NTOK + n0 + n)) * CCH + c0 + cb];
        *(int4*)dst = *(int4*)&tmp[0];
        *(int4*)(dst + 8) = *(int4*)&tmp[8];
    } else if (id < 2112) {
        const int w = id - 1536;
        const int which = w / 144;
        const int idx = (w % 144) * 256 + tid;
        const float* s = which == 0 ? w0 : which == 1 ? w1 : which == 2 ? w2 : w3;
        short* d       = which == 0 ? o0 : which == 1 ? o1 : which == 2 ? o2 : o3;
        float4 v = ((const float4*)s)[idx];
        short4 o = make_short4(f2b(v.x), f2b(v.y), f2b(v.z), f2b(v.w));
        ((short4*)d)[idx] = o;
    } else {
        const int o = (id - 2112) * 1024 + tid * 4;
        float4 z = {0.f, 0.f, 0.f, 0.f};
        *(float4*)&amap[o] = z;
    }
}

// ---------------------------------------------------------------------------
// Fused QKV projection, 128x128 tiles. 576 blocks: b=id%8 (XCD-local),
// r=id/8: which=r/24 (0:Q,1:K tok-major; 2:V ch-major), tt=r%24.
// Q output pre-scaled by QSCALE. 32 KB LDS -> one residency round.
// ---------------------------------------------------------------------------
__global__ __launch_bounds__(256, 3) void gemm_qkv(
    const short* __restrict__ xtq, const short* __restrict__ xtc,
    const short* __restrict__ wq, const short* __restrict__ wk,
    const short* __restrict__ wvm,
    short* __restrict__ qout, short* __restrict__ kout, short* __restrict__ vout)
{
    __shared__ __align__(16) short SMEM[16384];   // 32 KB: A | B, cbuf in epi
    const int id = blockIdx.x;
    const int b = id & 7, r = id >> 3;
    const int which = r / 24, tt = r % 24;

    const short *Ag, *Bg;
    short* out;
    size_t obase;
    int ostride;
    if (which < 2) {
        const int it = tt / 3, jt = tt % 3;
        const short* x = (which == 0) ? xtq : xtc;
        const short* W = (which == 0) ? wq : wk;
        Ag = x + ((size_t)(b * NTOK + it * 128)) * CCH;
        Bg = W + (size_t)(jt * 128) * CCH;
        out = (which == 0) ? qout : kout;
        obase = ((size_t)(b * NTOK + it * 128)) * CCH + jt * 128;
        ostride = CCH;
    } else {
        const int ct = tt % 3, nt = tt / 3;
        Ag = wvm + (size_t)(ct * 128) * CCH;
        Bg = xtc + ((size_t)(b * NTOK + nt * 128)) * CCH;
        out = vout;
        obase = ((size_t)(b * CCH + ct * 128)) * NTOK + nt * 128;
        ostride = NTOK;
    }

    f32x4 z4 = {0.f, 0.f, 0.f, 0.f};
    f32x4 acc[4][4];
#pragma unroll
    for (int si = 0; si < 4; ++si)
#pragma unroll
        for (int sj = 0; sj < 4; ++sj) acc[si][sj] = z4;

    gemm128_core(Ag, Bg, &SMEM[0], acc);

    if (which == 0) {
#pragma unroll
        for (int si = 0; si < 4; ++si)
#pragma unroll
            for (int sj = 0; sj < 4; ++sj)
#pragma unroll
                for (int rr = 0; rr < 4; ++rr)
                    acc[si][sj][rr] *= QSCALE;
    }
    epilogue_bf16(acc, &SMEM[0], out, obase, ostride);
}

// ---------------------------------------------------------------------------
// Attention O-pass — single pass, swapped-QK^T 32x32 MFMA, in-register P
// (vsplit operand pairing, verified r2), jsub-split schedule (verified r4),
// obuf aliased onto Vst (verified r5). NEW: s_setprio(1) around the compute
// cluster (T5; m191 attn +4-7% — our stage-vs-compute wave split is exactly
// the role diversity setprio needs).
// ---------------------------------------------------------------------------
__global__ __launch_bounds__(256, 3) void attn(
    const short* __restrict__ qt, const short* __restrict__ kt,
    const short* __restrict__ vc, short* __restrict__ omid,
    float* __restrict__ rws)
{
    __shared__ __align__(16) short Kst[2][4096];   // 16 KB (64 tok x 64 ch)
    __shared__ __align__(16) short Vst[2][4096];   // 16 KB; obuf alias in epi
    __shared__ float denbuf[4][64];                // 1 KB
    __shared__ float rden_sh[2][32];
    float (*obuf)[16][64] = (float (*)[16][64])(&Vst[0][0]);  // 16 KB alias

    const int tid = threadIdx.x, lane = tid & 63;
    const int l31 = lane & 31, hi = lane >> 5;
    const int wv = tid >> 6;
    const int isub = (wv & 1) * 32;
    const int js = wv >> 1;            // this wave's fixed jsub

    const int id = blockIdx.x;
    const int b = id & 7, rr_ = id >> 3;
    const int h = rr_ % 6, i0 = (rr_ / 6) * 64;

    const size_t hoff = (size_t)b * NTOK * CCH + h * DHEAD;
    const short* Kg = kt + hoff;                                   // stride CCH
    const short* Vg = vc + ((size_t)(b * CCH + h * DHEAD)) * NTOK; // stride NTOK

    // Q B-frags hoisted: lane holds Q[i = i0+isub+l31, d = m*16 + hi*8 ..+8]
    const short* qp = qt + hoff + (size_t)(i0 + isub + l31) * CCH + hi * 8;
    bf16x8 qf[4];
#pragma unroll
    for (int m = 0; m < 4; ++m) qf[m] = *(const bf16x8*)(qp + m * 16);

    // prologue: all 4 waves stage tile 0 (K and V)
    stage_tile(Kg, CCH, Kst[0], wv, lane);
    stage_tile(Vg, NTOK, Vst[0], wv, lane);
    __syncthreads();

    const f32x16 z16 = {0,0,0,0,0,0,0,0,0,0,0,0,0,0,0,0};
    f32x16 oacc0 = z16, oacc1 = z16;   // d 0..31 / 32..63
    float den = 0.f;

    for (int jt = 0; jt < 16; ++jt) {
        const int cur = jt & 1;
        // stage next tile first: js=0 waves bring K, js=1 waves bring V.
        if (jt < 15) {
            if (js == 0)
                stage_tile_2w(Kg + (size_t)(jt + 1) * 64 * CCH, CCH,
                              Kst[cur ^ 1], wv & 1, lane);
            else
                stage_tile_2w(Vg + (size_t)(jt + 1) * 64, NTOK,
                              Vst[cur ^ 1], wv & 1, lane);
        }
        // compute this wave's jsub on the current tile
        {
            const short* Kb = Kst[cur];
            const short* Vb = Vst[cur];
            __builtin_amdgcn_s_setprio(1);
            f32x16 s = z16;
#pragma unroll
            for (int m = 0; m < 4; ++m)
                s = MFMA32(frag_read(Kb, js * 32 + l31, 2 * m + hi), qf[m], s);
            bf16x8 pa0, pa1;
#pragma unroll
            for (int e = 0; e < 8; ++e) {
                const float x0 = EXP2(s[e]);
                const float x1 = EXP2(s[8 + e]);
                den += x0 + x1;
                pa0[e] = (__bf16)x0;
                pa1[e] = (__bf16)x1;
            }
            oacc0 = MFMA32(pa0, vsplit(Vb, l31,      js * 4,     hi), oacc0);
            oacc0 = MFMA32(pa1, vsplit(Vb, l31,      js * 4 + 2, hi), oacc0);
            oacc1 = MFMA32(pa0, vsplit(Vb, 32 + l31, js * 4,     hi), oacc1);
            oacc1 = MFMA32(pa1, vsplit(Vb, 32 + l31, js * 4 + 2, hi), oacc1);
            __builtin_amdgcn_s_setprio(0);
        }
        __syncthreads();
    }

    // ---- epilogue: cross-js combine, normalize, store (verified r2/r5) ----
    const int dh = js;                 // this wave finalizes d-half dh
    if (dh == 0) {
#pragma unroll
        for (int g2 = 0; g2 < 16; ++g2) obuf[wv][g2][lane] = oacc1[g2];
    } else {
#pragma unroll
        for (int g2 = 0; g2 < 16; ++g2) obuf[wv][g2][lane] = oacc0[g2];
    }
    denbuf[wv][lane] = den;
    __syncthreads();

    const int g = wv & 1;
    const float dtot = denbuf[g][l31] + denbuf[g][l31 + 32]
                     + denbuf[g | 2][l31] + denbuf[g | 2][l31 + 32];
    const float rden = 1.0f / dtot;
    if (wv < 2 && lane < 32) {
        rden_sh[wv][lane] = rden;
        rws[((b * 6 + h) << 10) + i0 + isub + lane] = rden;
    }
    __syncthreads();

#pragma unroll
    for (int reg = 0; reg < 16; ++reg) {
        const int crw = (reg & 3) + 8 * (reg >> 2) + 4 * hi;     // i-local 0..31
        const float rd = rden_sh[g][crw];
        const float okeep = (dh == 0) ? oacc0[reg] : oacc1[reg];
        const float ov = (okeep + obuf[wv ^ 2][reg][lane]) * rd;
        omid[((size_t)(b * NTOK + i0 + isub + crw)) * CCH + h * DHEAD + dh * 32 + l31] =
            f2b(ov);
    }
}

// ---------------------------------------------------------------------------
// tail_k: o_proj (id<192) + amap (id>=192) merged — the two are independent
// (both depend only on attn), and o_proj alone is 192 blocks = 64 idle CUs +
// 12.5% occupancy on the rest. The 1536 short amap blocks backfill. One
// fewer launch. Shared 32 KB SMEM union (amap uses 16 KB Kst + 2 KB colbuf).
// Both bodies verbatim from the r5/r6-verified kernels.
// ---------------------------------------------------------------------------
__global__ __launch_bounds__(256, 3) void tail_k(
    const short* __restrict__ wo, const short* __restrict__ omid,
    const float* __restrict__ bias, float* __restrict__ Y,
    const short* __restrict__ qt, const short* __restrict__ kt,
    const float* __restrict__ rws, float* __restrict__ amap)
{
    __shared__ __align__(16) short SMEM[16384];   // 32 KB
    const int id = blockIdx.x, tid = threadIdx.x;

    if (id < 192) {
        // ---------------- o_proj part (verbatim r6) ----------------
        const int b = id & 7, r = id >> 3;
        const int ct = r % 3, nt = r / 3;

        const short* Ag = wo + (size_t)(ct * 128) * CCH;
        const short* Bg = omid + ((size_t)(b * NTOK + nt * 128)) * CCH;

        f32x4 z4 = {0.f, 0.f, 0.f, 0.f};
        f32x4 acc[4][4];
#pragma unroll
        for (int si = 0; si < 4; ++si)
#pragma unroll
            for (int sj = 0; sj < 4; ++sj) acc[si][sj] = z4;

        gemm128_core(Ag, Bg, &SMEM[0], acc);

        const int l15 = tid & 15, quad = (tid >> 4) & 3, wv = tid >> 6;
        const int wi = (wv >> 1) * 64, wj = (wv & 1) * 64;
#pragma unroll
        for (int si = 0; si < 4; ++si) {
#pragma unroll
            for (int rr = 0; rr < 4; ++rr) {
                const int ch = ct * 128 + wi + si * 16 + quad * 4 + rr;
                const float bv = bias[ch];
#pragma unroll
                for (int sj = 0; sj < 4; ++sj)
                    Y[((size_t)(b * CCH + ch)) * NTOK + nt * 128 + wj + sj * 16 + l15] =
                        acc[si][sj][rr] + bv;
            }
        }
    } else {
        // ---------------- amap part (verbatim r6, j-split) ----------------
        short (*Kst)[4096] = (short (*)[4096])(&SMEM[0]);           // 16 KB
        float (*colbuf)[4][64] = (float (*)[4][64])(&SMEM[8192]);   // 2 KB

        const int lane = tid & 63;
        const int l15 = tid & 15, quad = (tid >> 4) & 3, wv = tid >> 6;
        const int aid = id - 192;
        const int b = aid & 7, r = aid >> 3;        // r in 0..191
        const int h = r % 6, q = r / 6;             // q in 0..31
        const int i0 = (q >> 1) * 64;
        const int jt0 = (q & 1) * 8;

        const size_t hoff = (size_t)b * NTOK * CCH + h * DHEAD;
        const short* Kg = kt + hoff;
        const short* qp = qt + hoff + (size_t)(i0 + wv * 16 + l15) * CCH + quad * 8;
        const bf16x8 qa0 = *(const bf16x8*)qp;
        const bf16x8 qa1 = *(const bf16x8*)(qp + 32);

        float rdl[4];
#pragma unroll
        for (int rr = 0; rr < 4; ++rr)
            rdl[rr] = rws[((b * 6 + h) << 10) + i0 + wv * 16 + quad * 4 + rr];

        stage_tile(Kg + (size_t)jt0 * 64 * CCH, CCH, Kst[0], wv, lane);
        __syncthreads();

        for (int t = 0; t < 8; ++t) {
            const int jt = jt0 + t;
            const int cur = t & 1;
            if (t < 7)
                stage_tile(Kg + (size_t)(jt + 1) * 64 * CCH, CCH, Kst[cur ^ 1], wv, lane);
            f32x4 z4 = {0.f, 0.f, 0.f, 0.f};
            f32x4 s[4] = {z4, z4, z4, z4};
#pragma unroll
            for (int ns = 0; ns < 4; ++ns) {
                const int row = ns * 16 + l15;
                bf16x8 k0 = frag_read(Kst[cur], row, quad);
                bf16x8 k1 = frag_read(Kst[cur], row, quad + 4);
                s[ns] = MFMA16(qa0, k0, s[ns]);
                s[ns] = MFMA16(qa1, k1, s[ns]);
            }
#pragma unroll
            for (int ns = 0; ns < 4; ++ns) {
                float cs = EXP2(s[ns][0]) * rdl[0] + EXP2(s[ns][1]) * rdl[1]
                         + EXP2(s[ns][2]) * rdl[2] + EXP2(s[ns][3]) * rdl[3];
                cs += __shfl_xor(cs, 16);
                cs += __shfl_xor(cs, 32);
                if (quad == 0) colbuf[cur][wv][ns * 16 + l15] = cs;
            }
            __syncthreads();
            if (tid < 64) {
                const float tsum = colbuf[cur][0][tid] + colbuf[cur][1][tid]
                                 + colbuf[cur][2][tid] + colbuf[cur][3][tid];
                atomicAdd(amap + (size_t)b * NTOK + jt * 64 + tid,
                          tsum * (1.0f / (HEADS * NTOK)));
            }
        }
    }
}

// ---------------------------------------------------------------------------
extern "C" void kernel_launch(void* const* d_in, const int* in_sizes, int n_in,
                              void* d_out, int out_size, void* d_ws, size_t ws_size,
                              hipStream_t stream)
{
    const float* query   = (const float*)d_in[0];
    const float* context = (const float*)d_in[1];
    const float* Wq      = (const float*)d_in[2];
    const float* Wk      = (const float*)d_in[3];
    const float* Wv      = (const float*)d_in[4];
    const float* Wo      = (const float*)d_in[5];
    const float* bo      = (const float*)d_in[6];

    float* out = (float*)d_out;                          // [8,384,1024] fp32
    const size_t out_elems = (size_t)BATCH * CCH * NTOK;
    float* attn_map = out + out_elems;                   // [8,1024] fp32

    short* ws = (short*)d_ws;
    const size_t XT = (size_t)BATCH * NTOK * CCH;
    const size_t WSZ = (size_t)CCH * CCH;
    short* xtq  = ws;
    short* xtc  = xtq + XT;
    short* wqb  = xtc + XT;
    short* wkb  = wqb + WSZ;
    short* wvb  = wkb + WSZ;
    short* wob  = wvb + WSZ;
    short* qtb  = wob + WSZ;
    short* ktb  = qtb + XT;
    short* vcb  = ktb + XT;
    short* omid = vcb + XT;
    float* rws  = (float*)(omid + XT);                   // [8*6*1024] fp32 rden

    const dim3 blk(256);

    prep<<<dim3(2120), blk, 0, stream>>>(query, context, Wq, Wk, Wv, Wo,
                                         xtq, xtc, wqb, wkb, wvb, wob, attn_map);

    gemm_qkv<<<dim3(576), blk, 0, stream>>>(xtq, xtc, wqb, wkb, wvb,
                                            qtb, ktb, vcb);

    attn<<<dim3(768), blk, 0, stream>>>(qtb, ktb, vcb, omid, rws);

    tail_k<<<dim3(1728), blk, 0, stream>>>(wob, omid, bo, out,
                                           qtb, ktb, rws, attn_map);
}

// Round 8
// 137.648 us; speedup vs baseline: 1.2273x; 1.0275x over previous
//
#include <hip/hip_runtime.h>

// Problem constants
#define BATCH 8
#define CCH   384      // channels C == INNER
#define NTOK  1024     // H*W
#define HEADS 6
#define DHEAD 64
// softmax scale 1/8 and log2(e) folded into Q at projection time:
// qout = Q * 0.125 * 1.4426950408889634, attn uses exp2(s) = bare v_exp.
#define QSCALE 0.18033688011112042f

typedef __bf16 bf16x8 __attribute__((ext_vector_type(8)));
typedef float  f32x4  __attribute__((ext_vector_type(4)));
typedef float  f32x16 __attribute__((ext_vector_type(16)));

#define MFMA16(a, b, c) __builtin_amdgcn_mfma_f32_16x16x32_bf16((a), (b), (c), 0, 0, 0)
#define MFMA32(a, b, c) __builtin_amdgcn_mfma_f32_32x32x16_bf16((a), (b), (c), 0, 0, 0)
#define EXP2(x) __builtin_amdgcn_exp2f(x)

// fp32 -> bf16 RNE, raw bits
__device__ __forceinline__ short f2b(float x) {
    unsigned u = __float_as_uint(x);
    u += 0x7fffu + ((u >> 16) & 1u);
    return (short)(u >> 16);
}

// async global->LDS, 16B/lane. LDS dst = wave-uniform base + lane*16.
__device__ __forceinline__ void gld_lds16(const short* gp, short* lp) {
    __builtin_amdgcn_global_load_lds(
        (const __attribute__((address_space(1))) void*)gp,
        (__attribute__((address_space(3))) void*)lp, 16, 0, 0);
}

// ---- 64x64 xor-swizzled tile staging (4 waves) — verified r3/r4 ----
__device__ __forceinline__ void stage_tile(const short* gbase, size_t gstride,
                                           short* lbase, int wv, int lane) {
#pragma unroll
    for (int t = 0; t < 2; ++t) {
        const int row = t * 8 + (lane >> 3);
        const int c   = (lane & 7) ^ (row & 7);
        gld_lds16(gbase + (size_t)(wv * 16 + row) * gstride + c * 8,
                  lbase + (wv * 16 + t * 8) * 64);
    }
}
// same tile, staged by 2 waves (sw = 0/1), 4 gld per thread
__device__ __forceinline__ void stage_tile_2w(const short* gbase, size_t gstride,
                                              short* lbase, int sw, int lane) {
#pragma unroll
    for (int t = 0; t < 4; ++t) {
        const int row = sw * 32 + t * 8 + (lane >> 3);
        const int c   = (lane & 7) ^ (row & 7);
        gld_lds16(gbase + (size_t)row * gstride + c * 8,
                  lbase + (sw * 32 + t * 8) * 64);
    }
}
__device__ __forceinline__ bf16x8 frag_read(const short* lbase, int row, int c) {
    const int pc = c ^ (row & 7);
    return *(const bf16x8*)(lbase + row * 64 + pc * 8);
}

// Split V fragment read: element e of result holds V[row][tok], tok matching
// the NATURAL post-QK P register order: slots (hi, e) <-> j_local =
// [0,1,2,3,8,9,10,11][e] + 4*hi within the 16-token chunk starting at c0*8.
// Two 8B reads: chunk c0 half hi, chunk c0+1 half hi (xor-swizzled rows).
__device__ __forceinline__ bf16x8 vsplit(const short* lbase, int row, int c0, int hi) {
    const int r7 = row & 7;
    const int pc0 = c0 ^ r7, pc1 = (c0 + 1) ^ r7;
    const unsigned* b = (const unsigned*)(lbase + row * 64);
    const int o0 = pc0 * 4 + hi * 2;   // dword offset within the 32-dword row
    const int o1 = pc1 * 4 + hi * 2;
    union { unsigned u[4]; bf16x8 v; } t;
    t.u[0] = b[o0]; t.u[1] = b[o0 + 1];
    t.u[2] = b[o1]; t.u[3] = b[o1 + 1];
    return t.v;
}

// ---------------------------------------------------------------------------
// gemm128 core: C[128x128] = A[128x384] · B[128x384]^T, both k-contig rows,
// stride CCH. SINGLE-buffered phased loop (stage -> bar -> compute -> bar),
// 32 KB LDS -> 3 blocks/CU. Cross-block wave overlap (m114) replaces the
// intra-block double buffer. S layout: A at S[0..8191], B at S[8192..16383].
// ---------------------------------------------------------------------------
__device__ __forceinline__ void gemm128_core(
    const short* __restrict__ Ag, const short* __restrict__ Bg,
    short* S, f32x4 acc[4][4])
{
    const int tid = threadIdx.x, lane = tid & 63;
    const int l15 = tid & 15, quad = (tid >> 4) & 3, wv = tid >> 6;

#pragma unroll
    for (int kc = 0; kc < 6; ++kc) {
        stage_tile(Ag + kc * 64, CCH, S, wv, lane);
        stage_tile(Ag + kc * 64 + 64 * CCH, CCH, S + 4096, wv, lane);
        stage_tile(Bg + kc * 64, CCH, S + 8192, wv, lane);
        stage_tile(Bg + kc * 64 + 64 * CCH, CCH, S + 12288, wv, lane);
        __syncthreads();
        const short* Atile = S + (wv >> 1) * 4096;          // wi tile
        const short* Btile = S + 8192 + (wv & 1) * 4096;    // wj tile
#pragma unroll
        for (int h = 0; h < 2; ++h) {
            bf16x8 a[4], b[4];
#pragma unroll
            for (int s = 0; s < 4; ++s) {
                a[s] = frag_read(Atile, s * 16 + l15, h * 4 + quad);
                b[s] = frag_read(Btile, s * 16 + l15, h * 4 + quad);
            }
#pragma unroll
            for (int si = 0; si < 4; ++si)
#pragma unroll
                for (int sj = 0; sj < 4; ++sj)
                    acc[si][sj] = MFMA16(a[si], b[sj], acc[si][sj]);
        }
        __syncthreads();
    }
}

// Epilogue: repack the 128x128 bf16 C-tile through cbuf (= the 32 KB SMEM,
// free after the K-loop) so global stores are b128.
__device__ __forceinline__ void epilogue_bf16(
    f32x4 acc[4][4], short* cbuf,
    short* __restrict__ out, size_t obase, int ostride)
{
    const int tid = threadIdx.x;
    const int l15 = tid & 15, quad = (tid >> 4) & 3, wv = tid >> 6;
    const int wi = (wv >> 1) * 64, wj = (wv & 1) * 64;
    __syncthreads();
#pragma unroll
    for (int si = 0; si < 4; ++si)
#pragma unroll
        for (int sj = 0; sj < 4; ++sj)
#pragma unroll
            for (int rr = 0; rr < 4; ++rr)
                cbuf[(wi + si * 16 + quad * 4 + rr) * 128 + wj + sj * 16 + l15] =
                    f2b(acc[si][sj][rr]);
    __syncthreads();
#pragma unroll
    for (int pass = 0; pass < 8; ++pass) {
        const int row = pass * 16 + (tid >> 4);     // 0..127
        bf16x8 vchunk = *(const bf16x8*)(cbuf + row * 128 + l15 * 8);
        *(bf16x8*)(out + obase + (size_t)row * ostride + l15 * 8) = vchunk;
    }
}

// ---------------------------------------------------------------------------
// prep: fused transpose+convert (id<1536), weight convert (id<2112),
// amap zero (id>=2112). grid 2120.
// ---------------------------------------------------------------------------
__global__ __launch_bounds__(256) void prep(
    const float* __restrict__ Xq, const float* __restrict__ Xc,
    const float* __restrict__ w0, const float* __restrict__ w1,
    const float* __restrict__ w2, const float* __restrict__ w3,
    short* __restrict__ Xtq, short* __restrict__ Xtc,
    short* __restrict__ o0, short* __restrict__ o1,
    short* __restrict__ o2, short* __restrict__ o3,
    float* __restrict__ amap)
{
    __shared__ float tile[64][65];
    const int id = blockIdx.x, tid = threadIdx.x;
    if (id < 1536) {
        const int zz = id % 16, t = id / 16;
        const int n0 = (t % 16) * 64, c0 = (t / 16) * 64;
        const float* X = (zz < 8) ? Xq : Xc;
        short* Xt      = (zz < 8) ? Xtq : Xtc;
        const int b = zz & 7;
        const int tx = tid & 15, ty = tid >> 4;
#pragma unroll
        for (int rr = 0; rr < 4; ++rr) {
            const int c = rr * 16 + ty;
            float4 v = *(const float4*)&X[((size_t)(b * CCH + c0 + c)) * NTOK + n0 + tx * 4];
            tile[c][tx * 4 + 0] = v.x; tile[c][tx * 4 + 1] = v.y;
            tile[c][tx * 4 + 2] = v.z; tile[c][tx * 4 + 3] = v.w;
        }
        __syncthreads();
        const int n = tid >> 2, cb = (tid & 3) * 16;
        short tmp[16];
#pragma unroll
        for (int cc = 0; cc < 16; ++cc) tmp[cc] = f2b(tile[cb + cc][n]);
        short* dst = &Xt[((size_t)(b * NTOK + n0 + n)) * CCH + c0 + cb];
        *(int4*)dst = *(int4*)&tmp[0];
        *(int4*)(dst + 8) = *(int4*)&tmp[8];
    } else if (id < 2112) {
        const int w = id - 1536;
        const int which = w / 144;
        const int idx = (w % 144) * 256 + tid;
        const float* s = which == 0 ? w0 : which == 1 ? w1 : which == 2 ? w2 : w3;
        short* d       = which == 0 ? o0 : which == 1 ? o1 : which == 2 ? o2 : o3;
        float4 v = ((const float4*)s)[idx];
        short4 o = make_short4(f2b(v.x), f2b(v.y), f2b(v.z), f2b(v.w));
        ((short4*)d)[idx] = o;
    } else {
        const int o = (id - 2112) * 1024 + tid * 4;
        float4 z = {0.f, 0.f, 0.f, 0.f};
        *(float4*)&amap[o] = z;
    }
}

// ---------------------------------------------------------------------------
// Fused QKV projection, 128x128 tiles. 576 blocks: b=id%8 (XCD-local),
// r=id/8: which=r/24 (0:Q,1:K tok-major; 2:V ch-major), tt=r%24.
// Q output pre-scaled by QSCALE. 32 KB LDS -> one residency round.
// ---------------------------------------------------------------------------
__global__ __launch_bounds__(256, 3) void gemm_qkv(
    const short* __restrict__ xtq, const short* __restrict__ xtc,
    const short* __restrict__ wq, const short* __restrict__ wk,
    const short* __restrict__ wvm,
    short* __restrict__ qout, short* __restrict__ kout, short* __restrict__ vout)
{
    __shared__ __align__(16) short SMEM[16384];   // 32 KB: A | B, cbuf in epi
    const int id = blockIdx.x;
    const int b = id & 7, r = id >> 3;
    const int which = r / 24, tt = r % 24;

    const short *Ag, *Bg;
    short* out;
    size_t obase;
    int ostride;
    if (which < 2) {
        const int it = tt / 3, jt = tt % 3;
        const short* x = (which == 0) ? xtq : xtc;
        const short* W = (which == 0) ? wq : wk;
        Ag = x + ((size_t)(b * NTOK + it * 128)) * CCH;
        Bg = W + (size_t)(jt * 128) * CCH;
        out = (which == 0) ? qout : kout;
        obase = ((size_t)(b * NTOK + it * 128)) * CCH + jt * 128;
        ostride = CCH;
    } else {
        const int ct = tt % 3, nt = tt / 3;
        Ag = wvm + (size_t)(ct * 128) * CCH;
        Bg = xtc + ((size_t)(b * NTOK + nt * 128)) * CCH;
        out = vout;
        obase = ((size_t)(b * CCH + ct * 128)) * NTOK + nt * 128;
        ostride = NTOK;
    }

    f32x4 z4 = {0.f, 0.f, 0.f, 0.f};
    f32x4 acc[4][4];
#pragma unroll
    for (int si = 0; si < 4; ++si)
#pragma unroll
        for (int sj = 0; sj < 4; ++sj) acc[si][sj] = z4;

    gemm128_core(Ag, Bg, &SMEM[0], acc);

    if (which == 0) {
#pragma unroll
        for (int si = 0; si < 4; ++si)
#pragma unroll
            for (int sj = 0; sj < 4; ++sj)
#pragma unroll
                for (int rr = 0; rr < 4; ++rr)
                    acc[si][sj][rr] *= QSCALE;
    }
    epilogue_bf16(acc, &SMEM[0], out, obase, ostride);
}

// ---------------------------------------------------------------------------
// Attention O-pass — swapped-QK^T 32x32 MFMA, in-register P (vsplit pairing,
// verified r2), jsub-split compute (verified r4), obuf aliased onto Vst
// (verified r5), setprio (r7). NEW (T4): 3-deep K/V ring + counted vmcnt +
// raw s_barrier — the staging loads issued at phase top are for tile jt+2,
// consumed two phases later; the end-of-phase wait is s_waitcnt vmcnt(4)
// (waits ONLY the tile-jt+1 loads, issued a full phase ago; newest 4 stay
// in flight across the barrier). Hazards:
//  RAW: each wave waits its own 4 via vmcnt before s_barrier; barrier
//       publishes all waves' LDS writes for buf (jt+1)%3.           [ok]
//  WAR: top-of-jt writes buf (jt+2)%3 == buf read in phase jt-1;
//       separated by the end-of-(jt-1) barrier (after compute).     [ok]
// Tail: vmcnt(0) at jt=13,14 (loads 2 phases old -> cheap); __syncthreads
// before the obuf alias drains everything.
// ---------------------------------------------------------------------------
__global__ __launch_bounds__(256, 3) void attn(
    const short* __restrict__ qt, const short* __restrict__ kt,
    const short* __restrict__ vc, short* __restrict__ omid,
    float* __restrict__ rws)
{
    __shared__ __align__(16) short Kst[3][4096];   // 24 KB (64 tok x 64 ch)
    __shared__ __align__(16) short Vst[3][4096];   // 24 KB; obuf alias in epi
    __shared__ float denbuf[4][64];                // 1 KB
    __shared__ float rden_sh[2][32];
    float (*obuf)[16][64] = (float (*)[16][64])(&Vst[0][0]);  // 16 KB alias

    const int tid = threadIdx.x, lane = tid & 63;
    const int l31 = lane & 31, hi = lane >> 5;
    const int wv = tid >> 6;
    const int isub = (wv & 1) * 32;
    const int js = wv >> 1;            // this wave's fixed jsub

    const int id = blockIdx.x;
    const int b = id & 7, rr_ = id >> 3;
    const int h = rr_ % 6, i0 = (rr_ / 6) * 64;

    const size_t hoff = (size_t)b * NTOK * CCH + h * DHEAD;
    const short* Kg = kt + hoff;                                   // stride CCH
    const short* Vg = vc + ((size_t)(b * CCH + h * DHEAD)) * NTOK; // stride NTOK

    // Q B-frags hoisted: lane holds Q[i = i0+isub+l31, d = m*16 + hi*8 ..+8]
    const short* qp = qt + hoff + (size_t)(i0 + isub + l31) * CCH + hi * 8;
    bf16x8 qf[4];
#pragma unroll
    for (int m = 0; m < 4; ++m) qf[m] = *(const bf16x8*)(qp + m * 16);

    // prologue: tile0 by all waves (4 loads/thread), tile1 js-split (4 more).
    stage_tile(Kg, CCH, Kst[0], wv, lane);
    stage_tile(Vg, NTOK, Vst[0], wv, lane);
    if (js == 0)
        stage_tile_2w(Kg + (size_t)64 * CCH, CCH, Kst[1], wv & 1, lane);
    else
        stage_tile_2w(Vg + 64, NTOK, Vst[1], wv & 1, lane);
    asm volatile("s_waitcnt vmcnt(4)" ::: "memory");   // tile0 landed; tile1 in flight
    __builtin_amdgcn_sched_barrier(0);
    __builtin_amdgcn_s_barrier();
    __builtin_amdgcn_sched_barrier(0);

    const f32x16 z16 = {0,0,0,0,0,0,0,0,0,0,0,0,0,0,0,0};
    f32x16 oacc0 = z16, oacc1 = z16;   // d 0..31 / 32..63
    float den = 0.f;

    for (int jt = 0; jt < 16; ++jt) {
        const int cur = jt % 3;
        // stage tile jt+2 into ring slot (jt+2)%3 (last read in phase jt-1)
        if (jt < 14) {
            const int nxt = (jt + 2) % 3;
            if (js == 0)
                stage_tile_2w(Kg + (size_t)(jt + 2) * 64 * CCH, CCH,
                              Kst[nxt], wv & 1, lane);
            else
                stage_tile_2w(Vg + (size_t)(jt + 2) * 64, NTOK,
                              Vst[nxt], wv & 1, lane);
        }
        // compute this wave's jsub on tile jt
        {
            const short* Kb = Kst[cur];
            const short* Vb = Vst[cur];
            __builtin_amdgcn_s_setprio(1);
            f32x16 s = z16;
#pragma unroll
            for (int m = 0; m < 4; ++m)
                s = MFMA32(frag_read(Kb, js * 32 + l31, 2 * m + hi), qf[m], s);
            bf16x8 pa0, pa1;
#pragma unroll
            for (int e = 0; e < 8; ++e) {
                const float x0 = EXP2(s[e]);
                const float x1 = EXP2(s[8 + e]);
                den += x0 + x1;
                pa0[e] = (__bf16)x0;
                pa1[e] = (__bf16)x1;
            }
            oacc0 = MFMA32(pa0, vsplit(Vb, l31,      js * 4,     hi), oacc0);
            oacc0 = MFMA32(pa1, vsplit(Vb, l31,      js * 4 + 2, hi), oacc0);
            oacc1 = MFMA32(pa0, vsplit(Vb, 32 + l31, js * 4,     hi), oacc1);
            oacc1 = MFMA32(pa1, vsplit(Vb, 32 + l31, js * 4 + 2, hi), oacc1);
            __builtin_amdgcn_s_setprio(0);
        }
        // end of phase: wait ONLY tile-jt+1 loads (issued a full phase ago);
        // the 4 newest (tile jt+2) stay in flight across the barrier.
        if (jt < 13)
            asm volatile("s_waitcnt vmcnt(4)" ::: "memory");
        else
            asm volatile("s_waitcnt vmcnt(0)" ::: "memory");
        __builtin_amdgcn_sched_barrier(0);
        __builtin_amdgcn_s_barrier();
        __builtin_amdgcn_sched_barrier(0);
    }
    __syncthreads();   // full drain + fence before obuf aliases Vst

    // ---- epilogue: cross-js combine, normalize, store (verified r2/r5) ----
    const int dh = js;                 // this wave finalizes d-half dh
    if (dh == 0) {
#pragma unroll
        for (int g2 = 0; g2 < 16; ++g2) obuf[wv][g2][lane] = oacc1[g2];
    } else {
#pragma unroll
        for (int g2 = 0; g2 < 16; ++g2) obuf[wv][g2][lane] = oacc0[g2];
    }
    denbuf[wv][lane] = den;
    __syncthreads();

    const int g = wv & 1;
    const float dtot = denbuf[g][l31] + denbuf[g][l31 + 32]
                     + denbuf[g | 2][l31] + denbuf[g | 2][l31 + 32];
    const float rden = 1.0f / dtot;
    if (wv < 2 && lane < 32) {
        rden_sh[wv][lane] = rden;
        rws[((b * 6 + h) << 10) + i0 + isub + lane] = rden;
    }
    __syncthreads();

#pragma unroll
    for (int reg = 0; reg < 16; ++reg) {
        const int crw = (reg & 3) + 8 * (reg >> 2) + 4 * hi;     // i-local 0..31
        const float rd = rden_sh[g][crw];
        const float okeep = (dh == 0) ? oacc0[reg] : oacc1[reg];
        const float ov = (okeep + obuf[wv ^ 2][reg][lane]) * rd;
        omid[((size_t)(b * NTOK + i0 + isub + crw)) * CCH + h * DHEAD + dh * 32 + l31] =
            f2b(ov);
    }
}

// ---------------------------------------------------------------------------
// tail_k: o_proj (id<192) + amap (id>=192) merged (verified r7). The 1536
// short amap blocks backfill the CUs o_proj leaves idle.
// ---------------------------------------------------------------------------
__global__ __launch_bounds__(256, 3) void tail_k(
    const short* __restrict__ wo, const short* __restrict__ omid,
    const float* __restrict__ bias, float* __restrict__ Y,
    const short* __restrict__ qt, const short* __restrict__ kt,
    const float* __restrict__ rws, float* __restrict__ amap)
{
    __shared__ __align__(16) short SMEM[16384];   // 32 KB
    const int id = blockIdx.x, tid = threadIdx.x;

    if (id < 192) {
        // ---------------- o_proj part (verbatim r6) ----------------
        const int b = id & 7, r = id >> 3;
        const int ct = r % 3, nt = r / 3;

        const short* Ag = wo + (size_t)(ct * 128) * CCH;
        const short* Bg = omid + ((size_t)(b * NTOK + nt * 128)) * CCH;

        f32x4 z4 = {0.f, 0.f, 0.f, 0.f};
        f32x4 acc[4][4];
#pragma unroll
        for (int si = 0; si < 4; ++si)
#pragma unroll
            for (int sj = 0; sj < 4; ++sj) acc[si][sj] = z4;

        gemm128_core(Ag, Bg, &SMEM[0], acc);

        const int l15 = tid & 15, quad = (tid >> 4) & 3, wv = tid >> 6;
        const int wi = (wv >> 1) * 64, wj = (wv & 1) * 64;
#pragma unroll
        for (int si = 0; si < 4; ++si) {
#pragma unroll
            for (int rr = 0; rr < 4; ++rr) {
                const int ch = ct * 128 + wi + si * 16 + quad * 4 + rr;
                const float bv = bias[ch];
#pragma unroll
                for (int sj = 0; sj < 4; ++sj)
                    Y[((size_t)(b * CCH + ch)) * NTOK + nt * 128 + wj + sj * 16 + l15] =
                        acc[si][sj][rr] + bv;
            }
        }
    } else {
        // ---------------- amap part (verbatim r6, j-split) ----------------
        short (*Kst)[4096] = (short (*)[4096])(&SMEM[0]);           // 16 KB
        float (*colbuf)[4][64] = (float (*)[4][64])(&SMEM[8192]);   // 2 KB

        const int lane = tid & 63;
        const int l15 = tid & 15, quad = (tid >> 4) & 3, wv = tid >> 6;
        const int aid = id - 192;
        const int b = aid & 7, r = aid >> 3;        // r in 0..191
        const int h = r % 6, q = r / 6;             // q in 0..31
        const int i0 = (q >> 1) * 64;
        const int jt0 = (q & 1) * 8;

        const size_t hoff = (size_t)b * NTOK * CCH + h * DHEAD;
        const short* Kg = kt + hoff;
        const short* qp = qt + hoff + (size_t)(i0 + wv * 16 + l15) * CCH + quad * 8;
        const bf16x8 qa0 = *(const bf16x8*)qp;
        const bf16x8 qa1 = *(const bf16x8*)(qp + 32);

        float rdl[4];
#pragma unroll
        for (int rr = 0; rr < 4; ++rr)
            rdl[rr] = rws[((b * 6 + h) << 10) + i0 + wv * 16 + quad * 4 + rr];

        stage_tile(Kg + (size_t)jt0 * 64 * CCH, CCH, Kst[0], wv, lane);
        __syncthreads();

        for (int t = 0; t < 8; ++t) {
            const int jt = jt0 + t;
            const int cur = t & 1;
            if (t < 7)
                stage_tile(Kg + (size_t)(jt + 1) * 64 * CCH, CCH, Kst[cur ^ 1], wv, lane);
            f32x4 z4 = {0.f, 0.f, 0.f, 0.f};
            f32x4 s[4] = {z4, z4, z4, z4};
#pragma unroll
            for (int ns = 0; ns < 4; ++ns) {
                const int row = ns * 16 + l15;
                bf16x8 k0 = frag_read(Kst[cur], row, quad);
                bf16x8 k1 = frag_read(Kst[cur], row, quad + 4);
                s[ns] = MFMA16(qa0, k0, s[ns]);
                s[ns] = MFMA16(qa1, k1, s[ns]);
            }
#pragma unroll
            for (int ns = 0; ns < 4; ++ns) {
                float cs = EXP2(s[ns][0]) * rdl[0] + EXP2(s[ns][1]) * rdl[1]
                         + EXP2(s[ns][2]) * rdl[2] + EXP2(s[ns][3]) * rdl[3];
                cs += __shfl_xor(cs, 16);
                cs += __shfl_xor(cs, 32);
                if (quad == 0) colbuf[cur][wv][ns * 16 + l15] = cs;
            }
            __syncthreads();
            if (tid < 64) {
                const float tsum = colbuf[cur][0][tid] + colbuf[cur][1][tid]
                                 + colbuf[cur][2][tid] + colbuf[cur][3][tid];
                atomicAdd(amap + (size_t)b * NTOK + jt * 64 + tid,
                          tsum * (1.0f / (HEADS * NTOK)));
            }
        }
    }
}

// ---------------------------------------------------------------------------
extern "C" void kernel_launch(void* const* d_in, const int* in_sizes, int n_in,
                              void* d_out, int out_size, void* d_ws, size_t ws_size,
                              hipStream_t stream)
{
    const float* query   = (const float*)d_in[0];
    const float* context = (const float*)d_in[1];
    const float* Wq      = (const float*)d_in[2];
    const float* Wk      = (const float*)d_in[3];
    const float* Wv      = (const float*)d_in[4];
    const float* Wo      = (const float*)d_in[5];
    const float* bo      = (const float*)d_in[6];

    float* out = (float*)d_out;                          // [8,384,1024] fp32
    const size_t out_elems = (size_t)BATCH * CCH * NTOK;
    float* attn_map = out + out_elems;                   // [8,1024] fp32

    short* ws = (short*)d_ws;
    const size_t XT = (size_t)BATCH * NTOK * CCH;
    const size_t WSZ = (size_t)CCH * CCH;
    short* xtq  = ws;
    short* xtc  = xtq + XT;
    short* wqb  = xtc + XT;
    short* wkb  = wqb + WSZ;
    short* wvb  = wkb + WSZ;
    short* wob  = wvb + WSZ;
    short* qtb  = wob + WSZ;
    short* ktb  = qtb + XT;
    short* vcb  = ktb + XT;
    short* omid = vcb + XT;
    float* rws  = (float*)(omid + XT);                   // [8*6*1024] fp32 rden

    const dim3 blk(256);

    prep<<<dim3(2120), blk, 0, stream>>>(query, context, Wq, Wk, Wv, Wo,
                                         xtq, xtc, wqb, wkb, wvb, wob, attn_map);

    gemm_qkv<<<dim3(576), blk, 0, stream>>>(xtq, xtc, wqb, wkb, wvb,
                                            qtb, ktb, vcb);

    attn<<<dim3(768), blk, 0, stream>>>(qtb, ktb, vcb, omid, rws);

    tail_k<<<dim3(1728), blk, 0, stream>>>(wob, omid, bo, out,
                                           qtb, ktb, rws, attn_map);
}